// Round 1
// baseline (1391.882 us; speedup 1.0000x reference)
//
#include <hip/hip_runtime.h>
#include <hip/hip_bf16.h>

#define NPTS 8192
#define KNN  20

// ---------------------------------------------------------------- kNN
// one block per query point; distances in LDS; 20 argmax passes.
__global__ __launch_bounds__(256) void knn_kernel(const float* __restrict__ x,
                                                  int* __restrict__ idx_out) {
    const int N = NPTS;
    const float* px = x + 64 * N;
    const float* py = x + 65 * N;
    const float* pz = x + 66 * N;
    int n = blockIdx.x;
    __shared__ float dist[NPTS];
    __shared__ float rv[256];
    __shared__ int   ri[256];

    float qx = px[n], qy = py[n], qz = pz[n];
    float xxn = qx * qx + qy * qy + qz * qz;
    for (int m = threadIdx.x; m < N; m += 256) {
        float dx = px[m], dy = py[m], dz = pz[m];
        float dot = qx * dx + qy * dy + qz * dz;
        float xxm = dx * dx + dy * dy + dz * dz;
        dist[m] = 2.f * dot - xxn - xxm;  // = -||q-m||^2, matches ref formula
    }
    __syncthreads();

    for (int j = 0; j < KNN; ++j) {
        float bv = -INFINITY; int bi = 0;
        for (int m = threadIdx.x; m < N; m += 256) {
            float v = dist[m];
            if (v > bv) { bv = v; bi = m; }   // first-seen (lowest idx) wins ties
        }
        rv[threadIdx.x] = bv; ri[threadIdx.x] = bi;
        __syncthreads();
        for (int s = 128; s > 0; s >>= 1) {
            if (threadIdx.x < s) {
                float ov = rv[threadIdx.x + s]; int oi = ri[threadIdx.x + s];
                float cv = rv[threadIdx.x];     int ci = ri[threadIdx.x];
                if (ov > cv || (ov == cv && oi < ci)) { rv[threadIdx.x] = ov; ri[threadIdx.x] = oi; }
            }
            __syncthreads();
        }
        if (threadIdx.x == 0) {
            idx_out[n * KNN + j] = ri[0];
            dist[ri[0]] = -INFINITY;
        }
        __syncthreads();
    }
}

// ---------------------------------------------------------------- projection
// P[n][o] (o<64): A = sum_c X[n,c]*W[o][c];  (o>=64): B = sum_c X[n,c]*W[o-64][Cin+c]
__global__ __launch_bounds__(256) void proj_kernel(const float* __restrict__ X,
                                                   int sn, int sc, int Cin,
                                                   const float* __restrict__ W,
                                                   float* __restrict__ P) {
    int gid = blockIdx.x * 256 + threadIdx.x;  // NPTS*128
    int n = gid >> 7;
    int o = gid & 127;
    int twoC = 2 * Cin;
    const float* w = (o < 64) ? (W + o * twoC) : (W + (o - 64) * twoC + Cin);
    const float* xr = X + n * sn;
    float acc = 0.f;
    for (int c = 0; c < Cin; ++c) acc = fmaf(xr[c * sc], w[c], acc);
    P[n * 128 + o] = acc;
}

// ---------------------------------------------------------------- edge-z
// z[n,k,o] = A[idx[n,k],o] - A[n,o] + B[n,o]; also per-block partial sums
__global__ __launch_bounds__(256) void zedge_kernel(const float* __restrict__ P,
                                                    const int* __restrict__ idx,
                                                    float* __restrict__ Z,
                                                    float* __restrict__ part,
                                                    int nPerBlock) {
    int tid = threadIdx.x;
    int o = tid & 63;
    float sum = 0.f, sumsq = 0.f;
    int n0 = blockIdx.x * nPerBlock;
    for (int ni = 0; ni < nPerBlock; ++ni) {
        int n = n0 + ni;
        float An = P[n * 128 + o];
        float Bn = P[n * 128 + 64 + o];
        float base = Bn - An;
        for (int kk = tid >> 6; kk < KNN; kk += 4) {
            int m = idx[n * KNN + kk];
            float z = P[m * 128 + o] + base;
            Z[(n * KNN + kk) * 64 + o] = z;
            sum += z;
            sumsq = fmaf(z, z, sumsq);
        }
    }
    __shared__ float s1[256], s2[256];
    s1[tid] = sum; s2[tid] = sumsq;
    __syncthreads();
    if (tid < 64) {
        float a = s1[tid] + s1[tid + 64] + s1[tid + 128] + s1[tid + 192];
        float b = s2[tid] + s2[tid + 64] + s2[tid + 128] + s2[tid + 192];
        part[blockIdx.x * 128 + tid]      = a;
        part[blockIdx.x * 128 + 64 + tid] = b;
    }
}

// ---------------------------------------------------------------- BN stats -> affine
__global__ __launch_bounds__(256) void stats_kernel(const float* __restrict__ part, int nblk,
                                                    float invM,
                                                    const float* __restrict__ g,
                                                    const float* __restrict__ b,
                                                    float* __restrict__ affine) {
    int tid = threadIdx.x, o = tid & 63, seg = tid >> 6;
    float s = 0.f, ss = 0.f;
    for (int i = seg; i < nblk; i += 4) {
        s  += part[i * 128 + o];
        ss += part[i * 128 + 64 + o];
    }
    __shared__ float s1[256], s2[256];
    s1[tid] = s; s2[tid] = ss;
    __syncthreads();
    if (tid < 64) {
        float sum  = s1[tid] + s1[tid + 64] + s1[tid + 128] + s1[tid + 192];
        float ssum = s2[tid] + s2[tid + 64] + s2[tid + 128] + s2[tid + 192];
        float mean = sum * invM;
        float var  = ssum * invM - mean * mean;
        float sc = g[tid] * rsqrtf(var + 1e-5f);
        affine[tid]      = sc;
        affine[64 + tid] = b[tid] - mean * sc;
    }
}

// ---------------------------------------------------------------- conv2/conv4 GEMM
// Zout[r][o] = sum_c lrelu(affine(Zin[r][c])) * W[o][c];  tile 128 rows x 64 cols
__global__ __launch_bounds__(256) void conv_gemm_kernel(const float* __restrict__ Zin,
                                                        const float* __restrict__ affine,
                                                        const float* __restrict__ W,
                                                        float* __restrict__ Zout,
                                                        float* __restrict__ part) {
    __shared__ float As[128][65];
    __shared__ float Ws[64][65];
    __shared__ float red[256];
    int tid = threadIdx.x;
    int r0 = blockIdx.x * 128;

    for (int i = tid; i < 4096; i += 256) Ws[i >> 6][i & 63] = W[i];
    for (int i = tid; i < 8192; i += 256) {
        int rr = i >> 6, cc = i & 63;
        float z = Zin[(r0 + rr) * 64 + cc];
        z = fmaf(z, affine[cc], affine[64 + cc]);
        As[rr][cc] = (z >= 0.f) ? z : 0.2f * z;
    }
    __syncthreads();

    int ty = tid >> 4, tx = tid & 15;
    float acc[8][4];
#pragma unroll
    for (int i = 0; i < 8; ++i)
#pragma unroll
        for (int j = 0; j < 4; ++j) acc[i][j] = 0.f;

    for (int c = 0; c < 64; ++c) {
        float a[8], bv[4];
#pragma unroll
        for (int i = 0; i < 8; ++i) a[i] = As[ty + 16 * i][c];
#pragma unroll
        for (int j = 0; j < 4; ++j) bv[j] = Ws[tx + 16 * j][c];
#pragma unroll
        for (int i = 0; i < 8; ++i)
#pragma unroll
            for (int j = 0; j < 4; ++j) acc[i][j] = fmaf(a[i], bv[j], acc[i][j]);
    }

    float csum[4] = {0, 0, 0, 0}, csq[4] = {0, 0, 0, 0};
#pragma unroll
    for (int i = 0; i < 8; ++i) {
#pragma unroll
        for (int j = 0; j < 4; ++j) {
            float v = acc[i][j];
            Zout[(r0 + ty + 16 * i) * 64 + (tx + 16 * j)] = v;
            csum[j] += v;
            csq[j] = fmaf(v, v, csq[j]);
        }
    }
#pragma unroll
    for (int j = 0; j < 4; ++j) {
        red[tid] = csum[j];
        __syncthreads();
        for (int s = 8; s > 0; s >>= 1) {
            if (ty < s) red[tid] += red[tid + 16 * s];
            __syncthreads();
        }
        if (ty == 0) part[blockIdx.x * 128 + tx + 16 * j] = red[tx];
        __syncthreads();
        red[tid] = csq[j];
        __syncthreads();
        for (int s = 8; s > 0; s >>= 1) {
            if (ty < s) red[tid] += red[tid + 16 * s];
            __syncthreads();
        }
        if (ty == 0) part[blockIdx.x * 128 + 64 + tx + 16 * j] = red[tx];
        __syncthreads();
    }
}

// ---------------------------------------------------------------- affine+lrelu+maxpool over k
__global__ __launch_bounds__(256) void pool_kernel(const float* __restrict__ Z,
                                                   const float* __restrict__ affine,
                                                   float* __restrict__ Xout) {
    int gid = blockIdx.x * 256 + threadIdx.x;  // NPTS*64
    int n = gid >> 6, o = gid & 63;
    float sc = affine[o], sh = affine[64 + o];
    float m = -INFINITY;
    const float* zp = Z + (long)n * KNN * 64 + o;
    for (int kk = 0; kk < KNN; ++kk) {
        float z = fmaf(zp[kk * 64], sc, sh);
        z = (z >= 0.f) ? z : 0.2f * z;
        m = fmaxf(m, z);
    }
    Xout[gid] = m;
}

// ---------------------------------------------------------------- final MLPs
__global__ __launch_bounds__(256) void mlp1_kernel(const float* __restrict__ x1,
                                                   const float* __restrict__ x2,
                                                   const float* __restrict__ x3,
                                                   const float* __restrict__ W9a,
                                                   const float* __restrict__ b9a,
                                                   float* __restrict__ H) {
    int gid = blockIdx.x * 256 + threadIdx.x;  // NPTS*128
    int n = gid >> 7, j = gid & 127;
    const float* w = W9a + j * 192;
    const float* f1 = x1 + n * 64;
    const float* f2 = x2 + n * 64;
    const float* f3 = x3 + n * 64;
    float acc = b9a[j];
    for (int c = 0; c < 64; ++c) acc = fmaf(f1[c], w[c], acc);
    for (int c = 0; c < 64; ++c) acc = fmaf(f2[c], w[64 + c], acc);
    for (int c = 0; c < 64; ++c) acc = fmaf(f3[c], w[128 + c], acc);
    H[gid] = fmaxf(acc, 0.f);
}

__global__ __launch_bounds__(256) void mlp2_kernel(const float* __restrict__ H,
                                                   const float* __restrict__ W9b,
                                                   const float* __restrict__ b9b,
                                                   float* __restrict__ out) {
    int gid = blockIdx.x * 256 + threadIdx.x;  // NPTS*16
    int n = gid >> 4, j = gid & 15;
    const float* w = W9b + j * 128;
    const float* h = H + n * 128;
    float acc = b9b[j];
    for (int c = 0; c < 128; ++c) acc = fmaf(h[c], w[c], acc);
    out[j * NPTS + n] = acc;
}

// ---------------------------------------------------------------- launch
extern "C" void kernel_launch(void* const* d_in, const int* in_sizes, int n_in,
                              void* d_out, int out_size, void* d_ws, size_t ws_size,
                              hipStream_t stream) {
    const float* x   = (const float*)d_in[0];
    const float* W1  = (const float*)d_in[2];
    const float* g1  = (const float*)d_in[3];
    const float* b1  = (const float*)d_in[4];
    const float* W2  = (const float*)d_in[5];
    const float* g2  = (const float*)d_in[6];
    const float* b2  = (const float*)d_in[7];
    const float* W3  = (const float*)d_in[8];
    const float* g3  = (const float*)d_in[9];
    const float* b3  = (const float*)d_in[10];
    const float* W4  = (const float*)d_in[11];
    const float* g4  = (const float*)d_in[12];
    const float* b4  = (const float*)d_in[13];
    const float* W5  = (const float*)d_in[14];
    const float* g5  = (const float*)d_in[15];
    const float* b5  = (const float*)d_in[16];
    const float* W9a = (const float*)d_in[17];
    const float* b9a = (const float*)d_in[18];
    const float* W9b = (const float*)d_in[19];
    const float* b9b = (const float*)d_in[20];
    float* out = (float*)d_out;

    char* ws = (char*)d_ws;
    const size_t ZSZ = (size_t)NPTS * KNN * 64 * 4;  // 41.9 MB
    int*   idx   = (int*)(ws + 0);                       // 655360 B
    float* P     = (float*)(ws + 655360);                // 4 MB
    float* Za    = (float*)(ws + 4849664);               // 42 MB
    float* Zb    = (float*)(ws + 4849664 + ZSZ);         // 42 MB
    float* partA = (float*)(ws + 88735744);              // 512*128*4
    float* partB = (float*)(ws + 88997888);              // 1280*128*4
    float* aff   = (float*)(ws + 89653248);              // 5*128*4
    float* x1b   = (float*)(ws + 89655808);              // 2 MB
    float* x2b   = (float*)(ws + 91752960);              // 2 MB
    float* x3b   = (float*)(ws + 93850112);              // 2 MB
    float* Hb    = (float*)(ws + 95947264);              // 4 MB
    (void)ws_size; (void)in_sizes; (void)n_in; (void)out_size;

    float* aff1 = aff;
    float* aff2 = aff + 128;
    float* aff3 = aff + 256;
    float* aff4 = aff + 384;
    float* aff5 = aff + 512;
    const float invM = 1.f / (float)(NPTS * KNN);

    knn_kernel<<<NPTS, 256, 0, stream>>>(x, idx);

    // stage 1: conv1 (67 -> 64 via edge decomposition) + conv2 + pool -> x1
    proj_kernel<<<NPTS * 128 / 256, 256, 0, stream>>>(x, 1, NPTS, 67, W1, P);
    zedge_kernel<<<512, 256, 0, stream>>>(P, idx, Za, partA, 16);
    stats_kernel<<<1, 256, 0, stream>>>(partA, 512, invM, g1, b1, aff1);
    conv_gemm_kernel<<<NPTS * KNN / 128, 256, 0, stream>>>(Za, aff1, W2, Zb, partB);
    stats_kernel<<<1, 256, 0, stream>>>(partB, NPTS * KNN / 128, invM, g2, b2, aff2);
    pool_kernel<<<NPTS * 64 / 256, 256, 0, stream>>>(Zb, aff2, x1b);

    // stage 2: conv3 + conv4 + pool -> x2
    proj_kernel<<<NPTS * 128 / 256, 256, 0, stream>>>(x1b, 64, 1, 64, W3, P);
    zedge_kernel<<<512, 256, 0, stream>>>(P, idx, Za, partA, 16);
    stats_kernel<<<1, 256, 0, stream>>>(partA, 512, invM, g3, b3, aff3);
    conv_gemm_kernel<<<NPTS * KNN / 128, 256, 0, stream>>>(Za, aff3, W4, Zb, partB);
    stats_kernel<<<1, 256, 0, stream>>>(partB, NPTS * KNN / 128, invM, g4, b4, aff4);
    pool_kernel<<<NPTS * 64 / 256, 256, 0, stream>>>(Zb, aff4, x2b);

    // stage 3: conv5 + pool -> x3
    proj_kernel<<<NPTS * 128 / 256, 256, 0, stream>>>(x2b, 64, 1, 64, W5, P);
    zedge_kernel<<<512, 256, 0, stream>>>(P, idx, Za, partA, 16);
    stats_kernel<<<1, 256, 0, stream>>>(partA, 512, invM, g5, b5, aff5);
    pool_kernel<<<NPTS * 64 / 256, 256, 0, stream>>>(Za, aff5, x3b);

    // final MLPs
    mlp1_kernel<<<NPTS * 128 / 256, 256, 0, stream>>>(x1b, x2b, x3b, W9a, b9a, Hb);
    mlp2_kernel<<<NPTS * 16 / 256, 256, 0, stream>>>(Hb, W9b, b9b, out);
}

// Round 4
// 736.535 us; speedup vs baseline: 1.8898x; 1.8898x over previous
//
#include <hip/hip_runtime.h>
#include <hip/hip_bf16.h>

#define NPTS 8192
#define KNN  20
#define CHUNK 2048
#define CAP 256

// Distance with R1-replicating association (x-first fma chains, fma(2,dot,-xxn)-xxm).
// One shared inline helper => bit-identical at every call site.
__device__ __forceinline__ float pair_dist(float qx, float qy, float qz, float xxn,
                                           float dx, float dy, float dz) {
    float dot = fmaf(qz, dz, fmaf(qy, dy, qx * dx));
    float xxm = fmaf(dz, dz, fmaf(dy, dy, dx * dx));
    return fmaf(2.f, dot, -xxn) - xxm;
}

__device__ __forceinline__ float self_sq(float qx, float qy, float qz) {
    return fmaf(qz, qz, fmaf(qy, qy, qx * qx));
}

// ---------------------------------------------------------------- weight transpose
__global__ __launch_bounds__(256) void transpose_weights(const float* __restrict__ W1,
                                                         const float* __restrict__ W3,
                                                         const float* __restrict__ W5,
                                                         const float* __restrict__ W9a,
                                                         const float* __restrict__ W9b,
                                                         float* __restrict__ Wt1,
                                                         float* __restrict__ Wt3,
                                                         float* __restrict__ Wt5,
                                                         float* __restrict__ W9at,
                                                         float* __restrict__ W9bt) {
    int gid = blockIdx.x * 256 + threadIdx.x;
    if (gid < 67 * 128) {
        int c = gid >> 7, o = gid & 127;
        Wt1[gid] = (o < 64) ? W1[o * 134 + c] : W1[(o - 64) * 134 + 67 + c];
        return;
    }
    gid -= 67 * 128;
    if (gid < 64 * 128) {
        int c = gid >> 7, o = gid & 127;
        Wt3[gid] = (o < 64) ? W3[o * 128 + c] : W3[(o - 64) * 128 + 64 + c];
        return;
    }
    gid -= 64 * 128;
    if (gid < 64 * 128) {
        int c = gid >> 7, o = gid & 127;
        Wt5[gid] = (o < 64) ? W5[o * 128 + c] : W5[(o - 64) * 128 + 64 + c];
        return;
    }
    gid -= 64 * 128;
    if (gid < 192 * 128) {
        int c = gid >> 7, j = gid & 127;
        W9at[gid] = W9a[j * 192 + c];
        return;
    }
    gid -= 192 * 128;
    if (gid < 128 * 16) {
        int c = gid >> 4, j = gid & 15;
        W9bt[gid] = W9b[j * 128 + c];
    }
}

// ---------------------------------------------------------------- kNN (threshold-pruned, exact)
__global__ __launch_bounds__(256) void knn_kernel(const float* __restrict__ x,
                                                  int* __restrict__ idx_out) {
    const int N = NPTS;
    const float* px = x + 64 * N;
    const float* py = x + 65 * N;
    const float* pz = x + 66 * N;
    __shared__ float cx[CHUNK], cy[CHUNK], cz[CHUNK];
    __shared__ float bufv[4][CAP];
    __shared__ int   bufi[4][CAP];
    int tid = threadIdx.x, wid = tid >> 6, lane = tid & 63;
    int q = blockIdx.x * 4 + wid;
    float qx = px[q], qy = py[q], qz = pz[q];
    float xxn = self_sq(qx, qy, qz);

    // pass 1: per-lane top-1 over its 128 candidates (disjoint sets across lanes)
    float mv = -INFINITY;
    for (int ch = 0; ch < NPTS / CHUNK; ++ch) {
        __syncthreads();
        for (int i = tid; i < CHUNK; i += 256) {
            int m = ch * CHUNK + i;
            cx[i] = px[m]; cy[i] = py[m]; cz[i] = pz[m];
        }
        __syncthreads();
        for (int t = 0; t < CHUNK / 64; ++t) {
            int i = t * 64 + lane;
            float d = pair_dist(qx, qy, qz, xxn, cx[i], cy[i], cz[i]);
            mv = fmaxf(mv, d);
        }
    }

    // theta = 20th largest of the 64 lane maxima (>= 20 distinct point values => theta <= v20)
    float sel = mv;
    float th = -INFINITY;
    for (int r = 0; r < KNN; ++r) {
        float v = sel;
#pragma unroll
        for (int m = 32; m >= 1; m >>= 1) v = fmaxf(v, __shfl_xor(v, m));
        th = v;
        unsigned long long b = __ballot(sel == v);
        if (lane == __ffsll(b) - 1) sel = -INFINITY;
    }
    th -= 1e-3f;  // belt-and-suspenders slack (d is bit-consistent; this only adds survivors)

    // pass 2: compact survivors (>= th) into LDS buffer
    int wcnt = 0;
    for (int ch = 0; ch < NPTS / CHUNK; ++ch) {
        __syncthreads();
        for (int i = tid; i < CHUNK; i += 256) {
            int m = ch * CHUNK + i;
            cx[i] = px[m]; cy[i] = py[m]; cz[i] = pz[m];
        }
        __syncthreads();
        for (int t = 0; t < CHUNK / 64; ++t) {
            int i = t * 64 + lane;
            float d = pair_dist(qx, qy, qz, xxn, cx[i], cy[i], cz[i]);
            bool p = (d >= th);
            unsigned long long mk = __ballot(p);
            if (p) {
                int pos = wcnt + __popcll(mk & ((1ull << lane) - 1));
                if (pos < CAP) { bufv[wid][pos] = d; bufi[wid][pos] = ch * CHUNK + i; }
            }
            wcnt += (int)__popcll(mk);
        }
    }

    if (wcnt <= CAP) {
        // pass 3: exact top-20 of survivors, lex order (value desc, index asc)
        float sv[4]; int si[4];
#pragma unroll
        for (int r = 0; r < 4; ++r) {
            int j = r * 64 + lane;
            bool ok = j < wcnt;
            sv[r] = ok ? bufv[wid][j] : -INFINITY;
            si[r] = ok ? bufi[wid][j] : 0x7fffffff;
        }
        for (int r = 0; r < KNN; ++r) {
            float lv = -INFINITY; int li = 0x7fffffff; int ls = -1;
#pragma unroll
            for (int s = 0; s < 4; ++s) {
                bool g = (sv[s] > lv) || (sv[s] == lv && si[s] < li);
                if (g) { lv = sv[s]; li = si[s]; ls = s; }
            }
            float wv = lv; int wi = li;
#pragma unroll
            for (int m = 32; m >= 1; m >>= 1) {
                float ov = __shfl_xor(wv, m); int oi = __shfl_xor(wi, m);
                if (ov > wv || (ov == wv && oi < wi)) { wv = ov; wi = oi; }
            }
            if (lv == wv && li == wi) {
#pragma unroll
                for (int s = 0; s < 4; ++s) if (s == ls) { sv[s] = -INFINITY; si[s] = 0x7fffffff; }
            }
            if (lane == 0) idx_out[q * KNN + r] = wi;
        }
    } else {
        // fallback (overflow): per-lane register top-20 + sorted-list wave merge (exact)
        float bv[KNN]; int bi[KNN];
#pragma unroll
        for (int j = 0; j < KNN; ++j) { bv[j] = -INFINITY; bi[j] = 0x7fffffff; }
        for (int t = 0; t < NPTS / 64; ++t) {
            int m = t * 64 + lane;
            float cv = pair_dist(qx, qy, qz, xxn, px[m], py[m], pz[m]);
            int ci = m;
            if (cv > bv[KNN - 1] || (cv == bv[KNN - 1] && ci < bi[KNN - 1])) {
#pragma unroll
                for (int j = 0; j < KNN; ++j) {
                    bool g = (cv > bv[j]) || (cv == bv[j] && ci < bi[j]);
                    float tv = bv[j]; int ti = bi[j];
                    if (g) { bv[j] = cv; bi[j] = ci; cv = tv; ci = ti; }
                }
            }
        }
        for (int r = 0; r < KNN; ++r) {
            float wv = bv[0]; int wi = bi[0];
#pragma unroll
            for (int m = 32; m >= 1; m >>= 1) {
                float ov = __shfl_xor(wv, m); int oi = __shfl_xor(wi, m);
                if (ov > wv || (ov == wv && oi < wi)) { wv = ov; wi = oi; }
            }
            if (bv[0] == wv && bi[0] == wi) {
#pragma unroll
                for (int j = 0; j < KNN - 1; ++j) { bv[j] = bv[j + 1]; bi[j] = bi[j + 1]; }
                bv[KNN - 1] = -INFINITY; bi[KNN - 1] = 0x7fffffff;
            }
            if (lane == 0) idx_out[q * KNN + r] = wi;
        }
    }
}

// ---------------------------------------------------------------- projection (coalesced Wt)
__global__ __launch_bounds__(256) void proj_kernel(const float* __restrict__ X,
                                                   int sn, int sc, int Cin,
                                                   const float* __restrict__ Wt,
                                                   float* __restrict__ P) {
    int gid = blockIdx.x * 256 + threadIdx.x;  // NPTS*128
    int n = gid >> 7;
    int o = gid & 127;
    const float* xr = X + n * sn;
    float acc = 0.f;
    for (int c = 0; c < Cin; ++c) acc = fmaf(xr[c * sc], Wt[c * 128 + o], acc);
    P[n * 128 + o] = acc;
}

// ---------------------------------------------------------------- edge-z
__global__ __launch_bounds__(256) void zedge_kernel(const float* __restrict__ P,
                                                    const int* __restrict__ idx,
                                                    float* __restrict__ Z,
                                                    float* __restrict__ part,
                                                    int nPerBlock) {
    int tid = threadIdx.x;
    int o = tid & 63;
    float sum = 0.f, sumsq = 0.f;
    int n0 = blockIdx.x * nPerBlock;
    for (int ni = 0; ni < nPerBlock; ++ni) {
        int n = n0 + ni;
        float An = P[n * 128 + o];
        float Bn = P[n * 128 + 64 + o];
        float base = Bn - An;
        for (int kk = tid >> 6; kk < KNN; kk += 4) {
            int m = idx[n * KNN + kk];
            float z = P[m * 128 + o] + base;
            Z[(n * KNN + kk) * 64 + o] = z;
            sum += z;
            sumsq = fmaf(z, z, sumsq);
        }
    }
    __shared__ float s1[256], s2[256];
    s1[tid] = sum; s2[tid] = sumsq;
    __syncthreads();
    if (tid < 64) {
        float a = s1[tid] + s1[tid + 64] + s1[tid + 128] + s1[tid + 192];
        float b = s2[tid] + s2[tid + 64] + s2[tid + 128] + s2[tid + 192];
        part[blockIdx.x * 128 + tid]      = a;
        part[blockIdx.x * 128 + 64 + tid] = b;
    }
}

// ---------------------------------------------------------------- BN stats -> affine
__global__ __launch_bounds__(256) void stats_kernel(const float* __restrict__ part, int nblk,
                                                    float invM,
                                                    const float* __restrict__ g,
                                                    const float* __restrict__ b,
                                                    float* __restrict__ affine) {
    int tid = threadIdx.x, o = tid & 63, seg = tid >> 6;
    float s = 0.f, ss = 0.f;
    for (int i = seg; i < nblk; i += 4) {
        s  += part[i * 128 + o];
        ss += part[i * 128 + 64 + o];
    }
    __shared__ float s1[256], s2[256];
    s1[tid] = s; s2[tid] = ss;
    __syncthreads();
    if (tid < 64) {
        float sum  = s1[tid] + s1[tid + 64] + s1[tid + 128] + s1[tid + 192];
        float ssum = s2[tid] + s2[tid + 64] + s2[tid + 128] + s2[tid + 192];
        float mean = sum * invM;
        float var  = ssum * invM - mean * mean;
        float sc = g[tid] * rsqrtf(var + 1e-5f);
        affine[tid]      = sc;
        affine[64 + tid] = b[tid] - mean * sc;
    }
}

// ---------------------------------------------------------------- conv2/conv4 GEMM (in-place safe)
__global__ __launch_bounds__(256) void conv_gemm_kernel(const float* __restrict__ Zin,
                                                        const float* __restrict__ affine,
                                                        const float* __restrict__ W,
                                                        float* __restrict__ Zout,
                                                        float* __restrict__ part) {
    __shared__ float As[128][65];
    __shared__ float Ws[64][65];
    __shared__ float red[256];
    int tid = threadIdx.x;
    int r0 = blockIdx.x * 128;

    for (int i = tid; i < 4096; i += 256) Ws[i >> 6][i & 63] = W[i];
    for (int i = tid; i < 8192; i += 256) {
        int rr = i >> 6, cc = i & 63;
        float z = Zin[(r0 + rr) * 64 + cc];
        z = fmaf(z, affine[cc], affine[64 + cc]);
        As[rr][cc] = (z >= 0.f) ? z : 0.2f * z;
    }
    __syncthreads();

    int ty = tid >> 4, tx = tid & 15;
    float acc[8][4];
#pragma unroll
    for (int i = 0; i < 8; ++i)
#pragma unroll
        for (int j = 0; j < 4; ++j) acc[i][j] = 0.f;

    for (int c = 0; c < 64; ++c) {
        float a[8], bv[4];
#pragma unroll
        for (int i = 0; i < 8; ++i) a[i] = As[ty + 16 * i][c];
#pragma unroll
        for (int j = 0; j < 4; ++j) bv[j] = Ws[tx + 16 * j][c];
#pragma unroll
        for (int i = 0; i < 8; ++i)
#pragma unroll
            for (int j = 0; j < 4; ++j) acc[i][j] = fmaf(a[i], bv[j], acc[i][j]);
    }

    float csum[4] = {0, 0, 0, 0}, csq[4] = {0, 0, 0, 0};
#pragma unroll
    for (int i = 0; i < 8; ++i) {
#pragma unroll
        for (int j = 0; j < 4; ++j) {
            float v = acc[i][j];
            Zout[(r0 + ty + 16 * i) * 64 + (tx + 16 * j)] = v;
            csum[j] += v;
            csq[j] = fmaf(v, v, csq[j]);
        }
    }
#pragma unroll
    for (int j = 0; j < 4; ++j) {
        red[tid] = csum[j];
        __syncthreads();
        for (int s = 8; s > 0; s >>= 1) {
            if (ty < s) red[tid] += red[tid + 16 * s];
            __syncthreads();
        }
        if (ty == 0) part[blockIdx.x * 128 + tx + 16 * j] = red[tx];
        __syncthreads();
        red[tid] = csq[j];
        __syncthreads();
        for (int s = 8; s > 0; s >>= 1) {
            if (ty < s) red[tid] += red[tid + 16 * s];
            __syncthreads();
        }
        if (ty == 0) part[blockIdx.x * 128 + 64 + tx + 16 * j] = red[tx];
        __syncthreads();
    }
}

// ---------------------------------------------------------------- affine+lrelu+maxpool over k
__global__ __launch_bounds__(256) void pool_kernel(const float* __restrict__ Z,
                                                   const float* __restrict__ affine,
                                                   float* __restrict__ Xout) {
    int gid = blockIdx.x * 256 + threadIdx.x;  // NPTS*64
    int n = gid >> 6, o = gid & 63;
    float sc = affine[o], sh = affine[64 + o];
    float m = -INFINITY;
    const float* zp = Z + (long)n * KNN * 64 + o;
    for (int kk = 0; kk < KNN; ++kk) {
        float z = fmaf(zp[kk * 64], sc, sh);
        z = (z >= 0.f) ? z : 0.2f * z;
        m = fmaxf(m, z);
    }
    Xout[gid] = m;
}

// ---------------------------------------------------------------- final MLPs (coalesced Wt)
__global__ __launch_bounds__(256) void mlp1_kernel(const float* __restrict__ x1,
                                                   const float* __restrict__ x2,
                                                   const float* __restrict__ x3,
                                                   const float* __restrict__ W9at,
                                                   const float* __restrict__ b9a,
                                                   float* __restrict__ H) {
    int gid = blockIdx.x * 256 + threadIdx.x;  // NPTS*128
    int n = gid >> 7, j = gid & 127;
    const float* f1 = x1 + n * 64;
    const float* f2 = x2 + n * 64;
    const float* f3 = x3 + n * 64;
    float acc = b9a[j];
    for (int c = 0; c < 64; ++c) acc = fmaf(f1[c], W9at[c * 128 + j], acc);
    for (int c = 0; c < 64; ++c) acc = fmaf(f2[c], W9at[(64 + c) * 128 + j], acc);
    for (int c = 0; c < 64; ++c) acc = fmaf(f3[c], W9at[(128 + c) * 128 + j], acc);
    H[gid] = fmaxf(acc, 0.f);
}

__global__ __launch_bounds__(256) void mlp2_kernel(const float* __restrict__ H,
                                                   const float* __restrict__ W9bt,
                                                   const float* __restrict__ b9b,
                                                   float* __restrict__ out) {
    int gid = blockIdx.x * 256 + threadIdx.x;  // NPTS*16
    int n = gid >> 4, j = gid & 15;
    const float* h = H + n * 128;
    float acc = b9b[j];
    for (int c = 0; c < 128; ++c) acc = fmaf(h[c], W9bt[c * 16 + j], acc);
    out[j * NPTS + n] = acc;
}

// ---------------------------------------------------------------- launch
extern "C" void kernel_launch(void* const* d_in, const int* in_sizes, int n_in,
                              void* d_out, int out_size, void* d_ws, size_t ws_size,
                              hipStream_t stream) {
    const float* x   = (const float*)d_in[0];
    const float* W1  = (const float*)d_in[2];
    const float* g1  = (const float*)d_in[3];
    const float* b1  = (const float*)d_in[4];
    const float* W2  = (const float*)d_in[5];
    const float* g2  = (const float*)d_in[6];
    const float* b2  = (const float*)d_in[7];
    const float* W3  = (const float*)d_in[8];
    const float* g3  = (const float*)d_in[9];
    const float* b3  = (const float*)d_in[10];
    const float* W4  = (const float*)d_in[11];
    const float* g4  = (const float*)d_in[12];
    const float* b4  = (const float*)d_in[13];
    const float* W5  = (const float*)d_in[14];
    const float* g5  = (const float*)d_in[15];
    const float* b5  = (const float*)d_in[16];
    const float* W9a = (const float*)d_in[17];
    const float* b9a = (const float*)d_in[18];
    const float* W9b = (const float*)d_in[19];
    const float* b9b = (const float*)d_in[20];
    float* out = (float*)d_out;

    char* ws = (char*)d_ws;
    int*   idx   = (int*)(ws + 0);                 // 655360
    float* P     = (float*)(ws + 655360);          // 4 MB
    float* Za    = (float*)(ws + 4849664);         // 42 MB
    float* part  = (float*)(ws + 46792704);        // 655360
    float* aff   = (float*)(ws + 47448064);        // 2560
    float* x1b   = (float*)(ws + 47450624);        // 2 MB
    float* x2b   = (float*)(ws + 49547776);        // 2 MB
    float* x3b   = (float*)(ws + 51644928);        // 2 MB
    float* Hb    = (float*)(ws + 53742080);        // 4 MB
    float* Wt1   = (float*)(ws + 57936384);        // 67*128*4
    float* Wt3   = (float*)(ws + 57970688);        // 64*128*4
    float* Wt5   = (float*)(ws + 58003456);        // 64*128*4
    float* W9at  = (float*)(ws + 58036224);        // 192*128*4
    float* W9bt  = (float*)(ws + 58134528);        // 128*16*4
    (void)ws_size; (void)in_sizes; (void)n_in; (void)out_size;

    float* aff1 = aff;
    float* aff2 = aff + 128;
    float* aff3 = aff + 256;
    float* aff4 = aff + 384;
    float* aff5 = aff + 512;
    const float invM = 1.f / (float)(NPTS * KNN);

    transpose_weights<<<202, 256, 0, stream>>>(W1, W3, W5, W9a, W9b, Wt1, Wt3, Wt5, W9at, W9bt);
    knn_kernel<<<NPTS / 4, 256, 0, stream>>>(x, idx);

    // stage 1
    proj_kernel<<<NPTS * 128 / 256, 256, 0, stream>>>(x, 1, NPTS, 67, Wt1, P);
    zedge_kernel<<<512, 256, 0, stream>>>(P, idx, Za, part, 16);
    stats_kernel<<<1, 256, 0, stream>>>(part, 512, invM, g1, b1, aff1);
    conv_gemm_kernel<<<NPTS * KNN / 128, 256, 0, stream>>>(Za, aff1, W2, Za, part);
    stats_kernel<<<1, 256, 0, stream>>>(part, NPTS * KNN / 128, invM, g2, b2, aff2);
    pool_kernel<<<NPTS * 64 / 256, 256, 0, stream>>>(Za, aff2, x1b);

    // stage 2
    proj_kernel<<<NPTS * 128 / 256, 256, 0, stream>>>(x1b, 64, 1, 64, Wt3, P);
    zedge_kernel<<<512, 256, 0, stream>>>(P, idx, Za, part, 16);
    stats_kernel<<<1, 256, 0, stream>>>(part, 512, invM, g3, b3, aff3);
    conv_gemm_kernel<<<NPTS * KNN / 128, 256, 0, stream>>>(Za, aff3, W4, Za, part);
    stats_kernel<<<1, 256, 0, stream>>>(part, NPTS * KNN / 128, invM, g4, b4, aff4);
    pool_kernel<<<NPTS * 64 / 256, 256, 0, stream>>>(Za, aff4, x2b);

    // stage 3
    proj_kernel<<<NPTS * 128 / 256, 256, 0, stream>>>(x2b, 64, 1, 64, Wt5, P);
    zedge_kernel<<<512, 256, 0, stream>>>(P, idx, Za, part, 16);
    stats_kernel<<<1, 256, 0, stream>>>(part, 512, invM, g5, b5, aff5);
    pool_kernel<<<NPTS * 64 / 256, 256, 0, stream>>>(Za, aff5, x3b);

    // final MLPs
    mlp1_kernel<<<NPTS * 128 / 256, 256, 0, stream>>>(x1b, x2b, x3b, W9at, b9a, Hb);
    mlp2_kernel<<<NPTS * 16 / 256, 256, 0, stream>>>(Hb, W9bt, b9b, out);
}

// Round 5
// 720.236 us; speedup vs baseline: 1.9325x; 1.0226x over previous
//
#include <hip/hip_runtime.h>
#include <hip/hip_bf16.h>

#define NPTS 8192
#define KNN  20
#define CHUNK 2048
#define CAP 128

// dist with R1-replicating association; xxm precomputed with the identical chain.
__device__ __forceinline__ float pair_dist4(float qx, float qy, float qz, float xxn,
                                            float4 c) {
    float dot = fmaf(qz, c.z, fmaf(qy, c.y, qx * c.x));
    return fmaf(2.f, dot, -xxn) - c.w;
}

__device__ __forceinline__ float self_sq(float dx, float dy, float dz) {
    return fmaf(dz, dz, fmaf(dy, dy, dx * dx));
}

__device__ __forceinline__ float lrelu(float v) { return (v >= 0.f) ? v : 0.2f * v; }

// ---------------------------------------------------------------- prep: pack points + weight transposes
__global__ __launch_bounds__(256) void prep_kernel(const float* __restrict__ x,
                                                   const float* __restrict__ W1,
                                                   const float* __restrict__ W3,
                                                   const float* __restrict__ W5,
                                                   const float* __restrict__ W9a,
                                                   const float* __restrict__ W9b,
                                                   float4* __restrict__ pk,
                                                   float* __restrict__ Wt1,
                                                   float* __restrict__ Wt3,
                                                   float* __restrict__ Wt5,
                                                   float* __restrict__ W9at,
                                                   float* __restrict__ W9bt) {
    int gid = blockIdx.x * 256 + threadIdx.x;
    if (gid < NPTS) {
        float dx = x[64 * NPTS + gid], dy = x[65 * NPTS + gid], dz = x[66 * NPTS + gid];
        pk[gid] = make_float4(dx, dy, dz, self_sq(dx, dy, dz));
        return;
    }
    gid -= NPTS;
    if (gid < 67 * 128) {
        int c = gid >> 7, o = gid & 127;
        Wt1[gid] = (o < 64) ? W1[o * 134 + c] : W1[(o - 64) * 134 + 67 + c];
        return;
    }
    gid -= 67 * 128;
    if (gid < 64 * 128) {
        int c = gid >> 7, o = gid & 127;
        Wt3[gid] = (o < 64) ? W3[o * 128 + c] : W3[(o - 64) * 128 + 64 + c];
        return;
    }
    gid -= 64 * 128;
    if (gid < 64 * 128) {
        int c = gid >> 7, o = gid & 127;
        Wt5[gid] = (o < 64) ? W5[o * 128 + c] : W5[(o - 64) * 128 + 64 + c];
        return;
    }
    gid -= 64 * 128;
    if (gid < 192 * 128) {
        int c = gid >> 7, j = gid & 127;
        W9at[gid] = W9a[j * 192 + c];
        return;
    }
    gid -= 192 * 128;
    if (gid < 128 * 16) {
        int c = gid >> 4, j = gid & 15;
        W9bt[gid] = W9b[j * 128 + c];
    }
}

// ---------------------------------------------------------------- kNN: 4 queries/wave, float4 LDS
__global__ __launch_bounds__(256) void knn_kernel(const float4* __restrict__ pk,
                                                  int* __restrict__ idx_out) {
    __shared__ float4 cpt[CHUNK];
    __shared__ float bufv[16][CAP];
    __shared__ int   bufi[16][CAP];
    int tid = threadIdx.x, wid = tid >> 6, lane = tid & 63;
    int qbase = blockIdx.x * 16 + wid * 4;

    float qx[4], qy[4], qz[4], xxn[4], mv[4];
#pragma unroll
    for (int qi = 0; qi < 4; ++qi) {
        float4 qp = pk[qbase + qi];
        qx[qi] = qp.x; qy[qi] = qp.y; qz[qi] = qp.z; xxn[qi] = qp.w;
        mv[qi] = -INFINITY;
    }

    // pass 1: per-lane top-1 per query (each lane covers a disjoint 128-candidate set)
    for (int ch = 0; ch < NPTS / CHUNK; ++ch) {
        __syncthreads();
        for (int i = tid; i < CHUNK; i += 256) cpt[i] = pk[ch * CHUNK + i];
        __syncthreads();
        for (int t = 0; t < CHUNK / 64; ++t) {
            float4 c = cpt[t * 64 + lane];
#pragma unroll
            for (int qi = 0; qi < 4; ++qi)
                mv[qi] = fmaxf(mv[qi], pair_dist4(qx[qi], qy[qi], qz[qi], xxn[qi], c));
        }
    }

    // theta per query: 20th largest of the 64 lane maxima (disjoint => theta <= v20)
    float th[4];
#pragma unroll
    for (int qi = 0; qi < 4; ++qi) {
        float sel = mv[qi];
        float t = -INFINITY;
        for (int r = 0; r < KNN; ++r) {
            float v = sel;
#pragma unroll
            for (int m = 32; m >= 1; m >>= 1) v = fmaxf(v, __shfl_xor(v, m));
            t = v;
            unsigned long long b = __ballot(sel == v);
            if (lane == __ffsll(b) - 1) sel = -INFINITY;
        }
        th[qi] = t - 1e-3f;
    }

    // pass 2: compact survivors per query
    int wcnt[4] = {0, 0, 0, 0};
    for (int ch = 0; ch < NPTS / CHUNK; ++ch) {
        __syncthreads();
        for (int i = tid; i < CHUNK; i += 256) cpt[i] = pk[ch * CHUNK + i];
        __syncthreads();
        for (int t = 0; t < CHUNK / 64; ++t) {
            int gi = ch * CHUNK + t * 64 + lane;
            float4 c = cpt[t * 64 + lane];
#pragma unroll
            for (int qi = 0; qi < 4; ++qi) {
                float d = pair_dist4(qx[qi], qy[qi], qz[qi], xxn[qi], c);
                bool p = (d >= th[qi]);
                unsigned long long mk = __ballot(p);
                if (p) {
                    int pos = wcnt[qi] + __popcll(mk & ((1ull << lane) - 1));
                    if (pos < CAP) { bufv[wid * 4 + qi][pos] = d; bufi[wid * 4 + qi][pos] = gi; }
                }
                wcnt[qi] += (int)__popcll(mk);
            }
        }
    }

#pragma unroll 1
    for (int qi = 0; qi < 4; ++qi) {
        int q = qbase + qi;
        if (wcnt[qi] <= CAP) {
            // exact top-20 of survivors, lex (value desc, index asc)
            float sv[2]; int si[2];
#pragma unroll
            for (int r = 0; r < 2; ++r) {
                int j = r * 64 + lane;
                bool ok = j < wcnt[qi];
                sv[r] = ok ? bufv[wid * 4 + qi][j] : -INFINITY;
                si[r] = ok ? bufi[wid * 4 + qi][j] : 0x7fffffff;
            }
            for (int r = 0; r < KNN; ++r) {
                float lv; int li; int ls;
                if (sv[0] > sv[1] || (sv[0] == sv[1] && si[0] < si[1])) { lv = sv[0]; li = si[0]; ls = 0; }
                else { lv = sv[1]; li = si[1]; ls = 1; }
                float wv = lv; int wi = li;
#pragma unroll
                for (int m = 32; m >= 1; m >>= 1) {
                    float ov = __shfl_xor(wv, m); int oi = __shfl_xor(wi, m);
                    if (ov > wv || (ov == wv && oi < wi)) { wv = ov; wi = oi; }
                }
                if (lv == wv && li == wi) {
                    if (ls == 0) { sv[0] = -INFINITY; si[0] = 0x7fffffff; }
                    else { sv[1] = -INFINITY; si[1] = 0x7fffffff; }
                }
                if (lane == 0) idx_out[q * KNN + r] = wi;
            }
        } else {
            // fallback (degenerate data): per-lane register top-20 + sorted wave merge
            float bv[KNN]; int bi[KNN];
#pragma unroll
            for (int j = 0; j < KNN; ++j) { bv[j] = -INFINITY; bi[j] = 0x7fffffff; }
            for (int t = 0; t < NPTS / 64; ++t) {
                int m = t * 64 + lane;
                float4 c = pk[m];
                float cv = pair_dist4(qx[qi], qy[qi], qz[qi], xxn[qi], c);
                int ci = m;
                if (cv > bv[KNN - 1] || (cv == bv[KNN - 1] && ci < bi[KNN - 1])) {
#pragma unroll
                    for (int j = 0; j < KNN; ++j) {
                        bool g = (cv > bv[j]) || (cv == bv[j] && ci < bi[j]);
                        float tv = bv[j]; int ti = bi[j];
                        if (g) { bv[j] = cv; bi[j] = ci; cv = tv; ci = ti; }
                    }
                }
            }
            for (int r = 0; r < KNN; ++r) {
                float wv = bv[0]; int wi = bi[0];
#pragma unroll
                for (int m = 32; m >= 1; m >>= 1) {
                    float ov = __shfl_xor(wv, m); int oi = __shfl_xor(wi, m);
                    if (ov > wv || (ov == wv && oi < wi)) { wv = ov; wi = oi; }
                }
                if (bv[0] == wv && bi[0] == wi) {
#pragma unroll
                    for (int j = 0; j < KNN - 1; ++j) { bv[j] = bv[j + 1]; bi[j] = bi[j + 1]; }
                    bv[KNN - 1] = -INFINITY; bi[KNN - 1] = 0x7fffffff;
                }
                if (lane == 0) idx_out[q * KNN + r] = wi;
            }
        }
    }
}

// ---------------------------------------------------------------- projection (coalesced Wt)
__global__ __launch_bounds__(256) void proj_kernel(const float* __restrict__ X,
                                                   int sn, int sc, int Cin,
                                                   const float* __restrict__ Wt,
                                                   float* __restrict__ P) {
    int gid = blockIdx.x * 256 + threadIdx.x;  // NPTS*128
    int n = gid >> 7;
    int o = gid & 127;
    const float* xr = X + n * sn;
    float acc = 0.f;
    for (int c = 0; c < Cin; ++c) acc = fmaf(xr[c * sc], Wt[c * 128 + o], acc);
    P[n * 128 + o] = acc;
}

// ---------------------------------------------------------------- edge-z stats only (no Z write)
__global__ __launch_bounds__(256) void zsum_kernel(const float* __restrict__ P,
                                                   const int* __restrict__ idx,
                                                   float* __restrict__ part,
                                                   int nPerBlock) {
    int tid = threadIdx.x;
    int o = tid & 63;
    float sum = 0.f, sumsq = 0.f;
    int n0 = blockIdx.x * nPerBlock;
    for (int ni = 0; ni < nPerBlock; ++ni) {
        int n = n0 + ni;
        float An = P[n * 128 + o];
        float Bn = P[n * 128 + 64 + o];
        float base = Bn - An;
        for (int kk = tid >> 6; kk < KNN; kk += 4) {
            int m = idx[n * KNN + kk];
            float z = P[m * 128 + o] + base;
            sum += z;
            sumsq = fmaf(z, z, sumsq);
        }
    }
    __shared__ float s1[256], s2[256];
    s1[tid] = sum; s2[tid] = sumsq;
    __syncthreads();
    if (tid < 64) {
        float a = s1[tid] + s1[tid + 64] + s1[tid + 128] + s1[tid + 192];
        float b = s2[tid] + s2[tid + 64] + s2[tid + 128] + s2[tid + 192];
        part[blockIdx.x * 128 + tid]      = a;
        part[blockIdx.x * 128 + 64 + tid] = b;
    }
}

// ---------------------------------------------------------------- BN stats -> affine
__global__ __launch_bounds__(256) void stats_kernel(const float* __restrict__ part, int nblk,
                                                    float invM,
                                                    const float* __restrict__ g,
                                                    const float* __restrict__ b,
                                                    float* __restrict__ affine) {
    int tid = threadIdx.x, o = tid & 63, seg = tid >> 6;
    float s = 0.f, ss = 0.f;
    for (int i = seg; i < nblk; i += 4) {
        s  += part[i * 128 + o];
        ss += part[i * 128 + 64 + o];
    }
    __shared__ float s1[256], s2[256];
    s1[tid] = s; s2[tid] = ss;
    __syncthreads();
    if (tid < 64) {
        float sum  = s1[tid] + s1[tid + 64] + s1[tid + 128] + s1[tid + 192];
        float ssum = s2[tid] + s2[tid + 64] + s2[tid + 128] + s2[tid + 192];
        float mean = sum * invM;
        float var  = ssum * invM - mean * mean;
        float sc = g[tid] * rsqrtf(var + 1e-5f);
        affine[tid]      = sc;
        affine[64 + tid] = b[tid] - mean * sc;
    }
}

// ---------------------------------------------------------------- conv GEMM with gathered A-tile
__global__ __launch_bounds__(256) void conv_gemm_kernel(const float* __restrict__ P,
                                                        const int* __restrict__ idx,
                                                        const float* __restrict__ affine,
                                                        const float* __restrict__ W,
                                                        float* __restrict__ Zout,
                                                        float* __restrict__ part) {
    __shared__ float As[128][68];
    __shared__ float Ws[64][68];
    __shared__ float saff[128];
    __shared__ float red[256];
    int tid = threadIdx.x;
    int r0 = blockIdx.x * 128;

    if (tid < 128) saff[tid] = affine[tid];
    for (int i2 = tid; i2 < 1024; i2 += 256) {
        int rr = i2 >> 4, c4 = (i2 & 15) * 4;
        *(float4*)&Ws[rr][c4] = *(const float4*)&W[rr * 64 + c4];
    }
    __syncthreads();
    for (int i2 = tid; i2 < 2048; i2 += 256) {
        int rr = i2 >> 4, c4 = (i2 & 15) * 4;
        int grow = r0 + rr;
        unsigned n = (unsigned)grow / 20u;
        int m = idx[grow];
        float4 zn = *(const float4*)&P[(size_t)m * 128 + c4];
        float4 an = *(const float4*)&P[(size_t)n * 128 + c4];
        float4 bn = *(const float4*)&P[(size_t)n * 128 + 64 + c4];
        float4 o;
        float z;
        z = zn.x + (bn.x - an.x); o.x = lrelu(fmaf(z, saff[c4 + 0], saff[64 + c4 + 0]));
        z = zn.y + (bn.y - an.y); o.y = lrelu(fmaf(z, saff[c4 + 1], saff[64 + c4 + 1]));
        z = zn.z + (bn.z - an.z); o.z = lrelu(fmaf(z, saff[c4 + 2], saff[64 + c4 + 2]));
        z = zn.w + (bn.w - an.w); o.w = lrelu(fmaf(z, saff[c4 + 3], saff[64 + c4 + 3]));
        *(float4*)&As[rr][c4] = o;
    }
    __syncthreads();

    int ty = tid >> 4, tx = tid & 15;
    float acc[8][4];
#pragma unroll
    for (int i = 0; i < 8; ++i)
#pragma unroll
        for (int j = 0; j < 4; ++j) acc[i][j] = 0.f;

    for (int c4 = 0; c4 < 64; c4 += 4) {
        float4 a4[8], w4[4];
#pragma unroll
        for (int i = 0; i < 8; ++i) a4[i] = *(const float4*)&As[ty + 16 * i][c4];
#pragma unroll
        for (int j = 0; j < 4; ++j) w4[j] = *(const float4*)&Ws[tx + 16 * j][c4];
#pragma unroll
        for (int i = 0; i < 8; ++i)
#pragma unroll
            for (int j = 0; j < 4; ++j) {
                acc[i][j] = fmaf(a4[i].x, w4[j].x, acc[i][j]);
                acc[i][j] = fmaf(a4[i].y, w4[j].y, acc[i][j]);
                acc[i][j] = fmaf(a4[i].z, w4[j].z, acc[i][j]);
                acc[i][j] = fmaf(a4[i].w, w4[j].w, acc[i][j]);
            }
    }

    float csum[4] = {0, 0, 0, 0}, csq[4] = {0, 0, 0, 0};
#pragma unroll
    for (int i = 0; i < 8; ++i) {
#pragma unroll
        for (int j = 0; j < 4; ++j) {
            float v = acc[i][j];
            Zout[(size_t)(r0 + ty + 16 * i) * 64 + (tx + 16 * j)] = v;
            csum[j] += v;
            csq[j] = fmaf(v, v, csq[j]);
        }
    }
#pragma unroll
    for (int j = 0; j < 4; ++j) {
        red[tid] = csum[j];
        __syncthreads();
        for (int s = 8; s > 0; s >>= 1) {
            if (ty < s) red[tid] += red[tid + 16 * s];
            __syncthreads();
        }
        if (ty == 0) part[blockIdx.x * 128 + tx + 16 * j] = red[tx];
        __syncthreads();
        red[tid] = csq[j];
        __syncthreads();
        for (int s = 8; s > 0; s >>= 1) {
            if (ty < s) red[tid] += red[tid + 16 * s];
            __syncthreads();
        }
        if (ty == 0) part[blockIdx.x * 128 + 64 + tx + 16 * j] = red[tx];
        __syncthreads();
    }
}

// ---------------------------------------------------------------- affine+lrelu+maxpool over k
__global__ __launch_bounds__(256) void pool_kernel(const float* __restrict__ Z,
                                                   const float* __restrict__ affine,
                                                   float* __restrict__ Xout) {
    int gid = blockIdx.x * 256 + threadIdx.x;  // NPTS*64
    int n = gid >> 6, o = gid & 63;
    float sc = affine[o], sh = affine[64 + o];
    float m = -INFINITY;
    const float* zp = Z + (size_t)n * KNN * 64 + o;
    for (int kk = 0; kk < KNN; ++kk) m = fmaxf(m, lrelu(fmaf(zp[kk * 64], sc, sh)));
    Xout[gid] = m;
}

// ---------------------------------------------------------------- stage-3 fused edge+affine+lrelu+pool
__global__ __launch_bounds__(256) void zpool_kernel(const float* __restrict__ P,
                                                    const int* __restrict__ idx,
                                                    const float* __restrict__ affine,
                                                    float* __restrict__ Xout) {
    int gid = blockIdx.x * 256 + threadIdx.x;  // NPTS*64
    int n = gid >> 6, o = gid & 63;
    float An = P[n * 128 + o];
    float Bn = P[n * 128 + 64 + o];
    float base = Bn - An;
    float sc = affine[o], sh = affine[64 + o];
    float mx = -INFINITY;
    for (int kk = 0; kk < KNN; ++kk) {
        int m = idx[n * KNN + kk];
        float z = P[m * 128 + o] + base;
        mx = fmaxf(mx, lrelu(fmaf(z, sc, sh)));
    }
    Xout[gid] = mx;
}

// ---------------------------------------------------------------- fused final MLP
__global__ __launch_bounds__(256) void mlp_kernel(const float* __restrict__ x1,
                                                  const float* __restrict__ x2,
                                                  const float* __restrict__ x3,
                                                  const float* __restrict__ W9at,
                                                  const float* __restrict__ b9a,
                                                  const float* __restrict__ W9bt,
                                                  const float* __restrict__ b9b,
                                                  float* __restrict__ out) {
    __shared__ float hs[2][128];
    int tid = threadIdx.x;
    int p = tid >> 7, j = tid & 127;
    int n = blockIdx.x * 2 + p;
    const float* f1 = x1 + n * 64;
    const float* f2 = x2 + n * 64;
    const float* f3 = x3 + n * 64;
    float acc = b9a[j];
    for (int c = 0; c < 64; ++c) acc = fmaf(f1[c], W9at[c * 128 + j], acc);
    for (int c = 0; c < 64; ++c) acc = fmaf(f2[c], W9at[(64 + c) * 128 + j], acc);
    for (int c = 0; c < 64; ++c) acc = fmaf(f3[c], W9at[(128 + c) * 128 + j], acc);
    hs[p][j] = fmaxf(acc, 0.f);
    __syncthreads();
    if (tid < 32) {
        int p2 = tid >> 4, j2 = tid & 15;
        int n2 = blockIdx.x * 2 + p2;
        float a = b9b[j2];
        for (int c = 0; c < 128; ++c) a = fmaf(hs[p2][c], W9bt[c * 16 + j2], a);
        out[j2 * NPTS + n2] = a;
    }
}

// ---------------------------------------------------------------- launch
extern "C" void kernel_launch(void* const* d_in, const int* in_sizes, int n_in,
                              void* d_out, int out_size, void* d_ws, size_t ws_size,
                              hipStream_t stream) {
    const float* x   = (const float*)d_in[0];
    const float* W1  = (const float*)d_in[2];
    const float* g1  = (const float*)d_in[3];
    const float* b1  = (const float*)d_in[4];
    const float* W2  = (const float*)d_in[5];
    const float* g2  = (const float*)d_in[6];
    const float* b2  = (const float*)d_in[7];
    const float* W3  = (const float*)d_in[8];
    const float* g3  = (const float*)d_in[9];
    const float* b3  = (const float*)d_in[10];
    const float* W4  = (const float*)d_in[11];
    const float* g4  = (const float*)d_in[12];
    const float* b4  = (const float*)d_in[13];
    const float* W5  = (const float*)d_in[14];
    const float* g5  = (const float*)d_in[15];
    const float* b5  = (const float*)d_in[16];
    const float* W9a = (const float*)d_in[17];
    const float* b9a = (const float*)d_in[18];
    const float* W9b = (const float*)d_in[19];
    const float* b9b = (const float*)d_in[20];
    float* out = (float*)d_out;

    char* ws = (char*)d_ws;
    int*    idx  = (int*)(ws + 0);                 // 655360
    float4* pk   = (float4*)(ws + 655360);         // 131072
    float*  P    = (float*)(ws + 786432);          // 4 MB
    float*  Zb   = (float*)(ws + 4980736);         // 42 MB
    float*  part = (float*)(ws + 46923776);        // 655360
    float*  aff  = (float*)(ws + 47579136);        // 2560
    float*  x1b  = (float*)(ws + 47581696);        // 2 MB
    float*  x2b  = (float*)(ws + 49678848);        // 2 MB
    float*  x3b  = (float*)(ws + 51776000);        // 2 MB
    float*  Wt1  = (float*)(ws + 53873152);        // 34304
    float*  Wt3  = (float*)(ws + 53907456);        // 32768
    float*  Wt5  = (float*)(ws + 53940224);        // 32768
    float*  W9at = (float*)(ws + 53972992);        // 98304
    float*  W9bt = (float*)(ws + 54071296);        // 8192
    (void)ws_size; (void)in_sizes; (void)n_in; (void)out_size;

    float* aff1 = aff;
    float* aff2 = aff + 128;
    float* aff3 = aff + 256;
    float* aff4 = aff + 384;
    float* aff5 = aff + 512;
    const float invM = 1.f / (float)(NPTS * KNN);

    prep_kernel<<<234, 256, 0, stream>>>(x, W1, W3, W5, W9a, W9b, pk, Wt1, Wt3, Wt5, W9at, W9bt);
    knn_kernel<<<NPTS / 16, 256, 0, stream>>>(pk, idx);

    // stage 1
    proj_kernel<<<NPTS * 128 / 256, 256, 0, stream>>>(x, 1, NPTS, 67, Wt1, P);
    zsum_kernel<<<512, 256, 0, stream>>>(P, idx, part, 16);
    stats_kernel<<<1, 256, 0, stream>>>(part, 512, invM, g1, b1, aff1);
    conv_gemm_kernel<<<NPTS * KNN / 128, 256, 0, stream>>>(P, idx, aff1, W2, Zb, part);
    stats_kernel<<<1, 256, 0, stream>>>(part, NPTS * KNN / 128, invM, g2, b2, aff2);
    pool_kernel<<<NPTS * 64 / 256, 256, 0, stream>>>(Zb, aff2, x1b);

    // stage 2
    proj_kernel<<<NPTS * 128 / 256, 256, 0, stream>>>(x1b, 64, 1, 64, Wt3, P);
    zsum_kernel<<<512, 256, 0, stream>>>(P, idx, part, 16);
    stats_kernel<<<1, 256, 0, stream>>>(part, 512, invM, g3, b3, aff3);
    conv_gemm_kernel<<<NPTS * KNN / 128, 256, 0, stream>>>(P, idx, aff3, W4, Zb, part);
    stats_kernel<<<1, 256, 0, stream>>>(part, NPTS * KNN / 128, invM, g4, b4, aff4);
    pool_kernel<<<NPTS * 64 / 256, 256, 0, stream>>>(Zb, aff4, x2b);

    // stage 3 (fused edge+pool, no Z materialization)
    proj_kernel<<<NPTS * 128 / 256, 256, 0, stream>>>(x2b, 64, 1, 64, Wt5, P);
    zsum_kernel<<<512, 256, 0, stream>>>(P, idx, part, 16);
    stats_kernel<<<1, 256, 0, stream>>>(part, 512, invM, g5, b5, aff5);
    zpool_kernel<<<NPTS * 64 / 256, 256, 0, stream>>>(P, idx, aff5, x3b);

    // fused final MLP
    mlp_kernel<<<NPTS / 2, 256, 0, stream>>>(x1b, x2b, x3b, W9at, b9a, W9bt, b9b, out);
}

// Round 6
// 392.525 us; speedup vs baseline: 3.5460x; 1.8349x over previous
//
#include <hip/hip_runtime.h>

#define NPTS 8192
#define KNN  20
#define CHUNK 1024
#define CAP 128
#define NREP 8

__device__ __forceinline__ float pair_dist4(float qx, float qy, float qz, float xxn, float4 c) {
    float dot = fmaf(qz, c.z, fmaf(qy, c.y, qx * c.x));
    return fmaf(2.f, dot, -xxn) - c.w;
}
__device__ __forceinline__ float self_sq(float dx, float dy, float dz) {
    return fmaf(dz, dz, fmaf(dy, dy, dx * dx));
}
__device__ __forceinline__ float lrelu(float v) { return (v >= 0.f) ? v : 0.2f * v; }

// per-block BN affine from 8-replica global sums
__device__ __forceinline__ void compute_affine(const float* __restrict__ gs,
                                               const float* __restrict__ g,
                                               const float* __restrict__ b,
                                               float* saff, int tid) {
    if (tid < 64) {
        float s = 0.f, ss = 0.f;
#pragma unroll
        for (int r = 0; r < NREP; ++r) { s += gs[r * 128 + tid]; ss += gs[r * 128 + 64 + tid]; }
        const float invM = 1.f / (float)(NPTS * KNN);
        float mean = s * invM;
        float var = ss * invM - mean * mean;
        float sc = g[tid] * rsqrtf(var + 1e-5f);
        saff[tid] = sc;
        saff[64 + tid] = b[tid] - mean * sc;
    }
}

// ---------------------------------------------------------------- prep
__global__ __launch_bounds__(256) void prep_kernel(const float* __restrict__ x,
                                                   const float* __restrict__ W1,
                                                   const float* __restrict__ W3,
                                                   const float* __restrict__ W5,
                                                   const float* __restrict__ W9a,
                                                   const float* __restrict__ W9b,
                                                   float4* __restrict__ pk,
                                                   float* __restrict__ Wt1,
                                                   float* __restrict__ Wt3,
                                                   float* __restrict__ Wt5,
                                                   float* __restrict__ W9at,
                                                   float* __restrict__ W9bt,
                                                   float* __restrict__ gsAll) {
    int gid = blockIdx.x * 256 + threadIdx.x;
    if (gid < NPTS) {
        float dx = x[64 * NPTS + gid], dy = x[65 * NPTS + gid], dz = x[66 * NPTS + gid];
        pk[gid] = make_float4(dx, dy, dz, self_sq(dx, dy, dz));
        return;
    }
    gid -= NPTS;
    if (gid < 67 * 128) {
        int c = gid >> 7, o = gid & 127;
        Wt1[gid] = (o < 64) ? W1[o * 134 + c] : W1[(o - 64) * 134 + 67 + c];
        return;
    }
    gid -= 67 * 128;
    if (gid < 64 * 128) {
        int c = gid >> 7, o = gid & 127;
        Wt3[gid] = (o < 64) ? W3[o * 128 + c] : W3[(o - 64) * 128 + 64 + c];
        return;
    }
    gid -= 64 * 128;
    if (gid < 64 * 128) {
        int c = gid >> 7, o = gid & 127;
        Wt5[gid] = (o < 64) ? W5[o * 128 + c] : W5[(o - 64) * 128 + 64 + c];
        return;
    }
    gid -= 64 * 128;
    if (gid < 192 * 128) {
        int c = gid >> 7, j = gid & 127;
        W9at[gid] = W9a[j * 192 + c];
        return;
    }
    gid -= 192 * 128;
    if (gid < 128 * 16) {
        int c = gid >> 4, j = gid & 15;
        W9bt[gid] = W9b[j * 128 + c];
        return;
    }
    gid -= 128 * 16;
    if (gid < 5 * NREP * 128) gsAll[gid] = 0.f;
}

// ---------------------------------------------------------------- kNN
__global__ __launch_bounds__(256) void knn_kernel(const float4* __restrict__ pk,
                                                  int* __restrict__ idx_out) {
    __shared__ float4 cpt[CHUNK];
    __shared__ float bufv[16][CAP];
    __shared__ int   bufi[16][CAP];
    int tid = threadIdx.x, wid = tid >> 6, lane = tid & 63;
    int qbase = blockIdx.x * 16 + wid * 4;

    float qx[4], qy[4], qz[4], xxn[4], mv[4];
#pragma unroll
    for (int qi = 0; qi < 4; ++qi) {
        float4 qp = pk[qbase + qi];
        qx[qi] = qp.x; qy[qi] = qp.y; qz[qi] = qp.z; xxn[qi] = qp.w;
        mv[qi] = -INFINITY;
    }

    for (int ch = 0; ch < NPTS / CHUNK; ++ch) {
        __syncthreads();
        for (int i = tid; i < CHUNK; i += 256) cpt[i] = pk[ch * CHUNK + i];
        __syncthreads();
        for (int t = 0; t < CHUNK / 64; ++t) {
            float4 c = cpt[t * 64 + lane];
#pragma unroll
            for (int qi = 0; qi < 4; ++qi)
                mv[qi] = fmaxf(mv[qi], pair_dist4(qx[qi], qy[qi], qz[qi], xxn[qi], c));
        }
    }

    float th[4];
#pragma unroll
    for (int qi = 0; qi < 4; ++qi) {
        float sel = mv[qi];
        float t = -INFINITY;
        for (int r = 0; r < KNN; ++r) {
            float v = sel;
#pragma unroll
            for (int m = 32; m >= 1; m >>= 1) v = fmaxf(v, __shfl_xor(v, m));
            t = v;
            unsigned long long bm = __ballot(sel == v);
            if (lane == __ffsll(bm) - 1) sel = -INFINITY;
        }
        th[qi] = t - 1e-3f;
    }

    int wcnt[4] = {0, 0, 0, 0};
    for (int ch = 0; ch < NPTS / CHUNK; ++ch) {
        __syncthreads();
        for (int i = tid; i < CHUNK; i += 256) cpt[i] = pk[ch * CHUNK + i];
        __syncthreads();
        for (int t = 0; t < CHUNK / 64; ++t) {
            int gi = ch * CHUNK + t * 64 + lane;
            float4 c = cpt[t * 64 + lane];
#pragma unroll
            for (int qi = 0; qi < 4; ++qi) {
                float d = pair_dist4(qx[qi], qy[qi], qz[qi], xxn[qi], c);
                bool p = (d >= th[qi]);
                unsigned long long mk = __ballot(p);
                if (p) {
                    int pos = wcnt[qi] + __popcll(mk & ((1ull << lane) - 1));
                    if (pos < CAP) { bufv[wid * 4 + qi][pos] = d; bufi[wid * 4 + qi][pos] = gi; }
                }
                wcnt[qi] += (int)__popcll(mk);
            }
        }
    }

#pragma unroll 1
    for (int qi = 0; qi < 4; ++qi) {
        int q = qbase + qi;
        if (wcnt[qi] <= CAP) {
            float sv[2]; int si[2];
#pragma unroll
            for (int r = 0; r < 2; ++r) {
                int j = r * 64 + lane;
                bool ok = j < wcnt[qi];
                sv[r] = ok ? bufv[wid * 4 + qi][j] : -INFINITY;
                si[r] = ok ? bufi[wid * 4 + qi][j] : 0x7fffffff;
            }
            for (int r = 0; r < KNN; ++r) {
                float lv; int li; int ls;
                if (sv[0] > sv[1] || (sv[0] == sv[1] && si[0] < si[1])) { lv = sv[0]; li = si[0]; ls = 0; }
                else { lv = sv[1]; li = si[1]; ls = 1; }
                float wv = lv; int wi = li;
#pragma unroll
                for (int m = 32; m >= 1; m >>= 1) {
                    float ov = __shfl_xor(wv, m); int oi = __shfl_xor(wi, m);
                    if (ov > wv || (ov == wv && oi < wi)) { wv = ov; wi = oi; }
                }
                if (lv == wv && li == wi) {
                    if (ls == 0) { sv[0] = -INFINITY; si[0] = 0x7fffffff; }
                    else { sv[1] = -INFINITY; si[1] = 0x7fffffff; }
                }
                if (lane == 0) idx_out[q * KNN + r] = wi;
            }
        } else {
            float bv[KNN]; int bi[KNN];
#pragma unroll
            for (int j = 0; j < KNN; ++j) { bv[j] = -INFINITY; bi[j] = 0x7fffffff; }
            for (int t = 0; t < NPTS / 64; ++t) {
                int m = t * 64 + lane;
                float4 c = pk[m];
                float cv = pair_dist4(qx[qi], qy[qi], qz[qi], xxn[qi], c);
                int ci = m;
                if (cv > bv[KNN - 1] || (cv == bv[KNN - 1] && ci < bi[KNN - 1])) {
#pragma unroll
                    for (int j = 0; j < KNN; ++j) {
                        bool gsel = (cv > bv[j]) || (cv == bv[j] && ci < bi[j]);
                        float tv = bv[j]; int ti = bi[j];
                        if (gsel) { bv[j] = cv; bi[j] = ci; cv = tv; ci = ti; }
                    }
                }
            }
            for (int r = 0; r < KNN; ++r) {
                float wv = bv[0]; int wi = bi[0];
#pragma unroll
                for (int m = 32; m >= 1; m >>= 1) {
                    float ov = __shfl_xor(wv, m); int oi = __shfl_xor(wi, m);
                    if (ov > wv || (ov == wv && oi < wi)) { wv = ov; wi = oi; }
                }
                if (bv[0] == wv && bi[0] == wi) {
#pragma unroll
                    for (int j = 0; j < KNN - 1; ++j) { bv[j] = bv[j + 1]; bi[j] = bi[j + 1]; }
                    bv[KNN - 1] = -INFINITY; bi[KNN - 1] = 0x7fffffff;
                }
                if (lane == 0) idx_out[q * KNN + r] = wi;
            }
        }
    }
}

// ---------------------------------------------------------------- projection: 8 points/block
__global__ __launch_bounds__(256) void proj_kernel(const float* __restrict__ X,
                                                   int sn, int sc, int Cin,
                                                   const float* __restrict__ Wt,
                                                   float* __restrict__ P) {
    int tid = threadIdx.x;
    int o = tid & 127;
    int h = tid >> 7;  // 0..1
    int n0 = blockIdx.x * 8 + h * 4;
    float acc[4] = {0.f, 0.f, 0.f, 0.f};
    for (int c = 0; c < Cin; ++c) {
        float w = Wt[c * 128 + o];
#pragma unroll
        for (int i = 0; i < 4; ++i) acc[i] = fmaf(X[(n0 + i) * sn + c * sc], w, acc[i]);
    }
#pragma unroll
    for (int i = 0; i < 4; ++i) P[(n0 + i) * 128 + o] = acc[i];
}

// ---------------------------------------------------------------- z stats (gather, atomic sums)
__global__ __launch_bounds__(256) void zsum_kernel(const float* __restrict__ P,
                                                   const int* __restrict__ idx,
                                                   float* __restrict__ gs) {
    int tid = threadIdx.x;
    int o = tid & 63;
    float sum = 0.f, sumsq = 0.f;
    int n0 = blockIdx.x * 16;
    for (int ni = 0; ni < 16; ++ni) {
        int n = n0 + ni;
        float An = P[n * 128 + o];
        float Bn = P[n * 128 + 64 + o];
        float base = Bn - An;
        for (int kk = tid >> 6; kk < KNN; kk += 4) {
            int m = idx[n * KNN + kk];
            float z = P[m * 128 + o] + base;
            sum += z;
            sumsq = fmaf(z, z, sumsq);
        }
    }
    __shared__ float s1[256], s2[256];
    s1[tid] = sum; s2[tid] = sumsq;
    __syncthreads();
    if (tid < 64) {
        float a = s1[tid] + s1[tid + 64] + s1[tid + 128] + s1[tid + 192];
        float b = s2[tid] + s2[tid + 64] + s2[tid + 128] + s2[tid + 192];
        float* g = gs + (blockIdx.x & (NREP - 1)) * 128;
        atomicAdd(g + tid, a);
        atomicAdd(g + 64 + tid, b);
    }
}

// ---------------------------------------------------------------- conv GEMM: 80-row n-aligned tile
// A = lrelu(affineIn(z_edge)); Zraw = A*W^T; writes per-(n,o) max/min + atomic sums of Zraw
__global__ __launch_bounds__(256) void conv_gemm_kernel(const float* __restrict__ P,
                                                        const int* __restrict__ idx,
                                                        const float* __restrict__ gsIn,
                                                        const float* __restrict__ gIn,
                                                        const float* __restrict__ bIn,
                                                        const float* __restrict__ W,
                                                        float* __restrict__ gsOut,
                                                        float* __restrict__ Mx,
                                                        float* __restrict__ Mn) {
    __shared__ float As[80][68];
    __shared__ float Ws[64][68];
    __shared__ float saff[128];
    int tid = threadIdx.x;
    int r0 = blockIdx.x * 80;

    compute_affine(gsIn, gIn, bIn, saff, tid);
    for (int i2 = tid; i2 < 1024; i2 += 256) {
        int rr = i2 >> 4, c4 = (i2 & 15) * 4;
        *(float4*)&Ws[rr][c4] = *(const float4*)&W[rr * 64 + c4];
    }
    __syncthreads();

    for (int i2 = tid; i2 < 1280; i2 += 256) {
        int rr = i2 >> 4, c4 = (i2 & 15) * 4;
        int grow = r0 + rr;
        int n = grow / 20;
        int m = idx[grow];
        float4 zn = *(const float4*)&P[(size_t)m * 128 + c4];
        float4 an = *(const float4*)&P[(size_t)n * 128 + c4];
        float4 bn = *(const float4*)&P[(size_t)n * 128 + 64 + c4];
        float4 ov; float z;
        z = zn.x + (bn.x - an.x); ov.x = lrelu(fmaf(z, saff[c4 + 0], saff[64 + c4 + 0]));
        z = zn.y + (bn.y - an.y); ov.y = lrelu(fmaf(z, saff[c4 + 1], saff[64 + c4 + 1]));
        z = zn.z + (bn.z - an.z); ov.z = lrelu(fmaf(z, saff[c4 + 2], saff[64 + c4 + 2]));
        z = zn.w + (bn.w - an.w); ov.w = lrelu(fmaf(z, saff[c4 + 3], saff[64 + c4 + 3]));
        *(float4*)&As[rr][c4] = ov;
    }
    __syncthreads();

    int ty = tid >> 4, tx = tid & 15;
    float acc[5][4];
#pragma unroll
    for (int i = 0; i < 5; ++i)
#pragma unroll
        for (int j = 0; j < 4; ++j) acc[i][j] = 0.f;

    for (int c4 = 0; c4 < 64; c4 += 4) {
        float4 a4[5], w4[4];
#pragma unroll
        for (int i = 0; i < 5; ++i) a4[i] = *(const float4*)&As[ty + 16 * i][c4];
#pragma unroll
        for (int j = 0; j < 4; ++j) w4[j] = *(const float4*)&Ws[tx + 16 * j][c4];
#pragma unroll
        for (int i = 0; i < 5; ++i)
#pragma unroll
            for (int j = 0; j < 4; ++j) {
                acc[i][j] = fmaf(a4[i].x, w4[j].x, acc[i][j]);
                acc[i][j] = fmaf(a4[i].y, w4[j].y, acc[i][j]);
                acc[i][j] = fmaf(a4[i].z, w4[j].z, acc[i][j]);
                acc[i][j] = fmaf(a4[i].w, w4[j].w, acc[i][j]);
            }
    }
    __syncthreads();  // all GEMM reads of As/Ws done

#pragma unroll
    for (int i = 0; i < 5; ++i)
#pragma unroll
        for (int j = 0; j < 4; ++j) As[ty + 16 * i][tx + 16 * j] = acc[i][j];
    __syncthreads();

    // scan: wave a handles point-group a (rows 20a..20a+19), lane o
    int a = tid >> 6, o = tid & 63;
    float mxv = -INFINITY, mnv = INFINITY, s = 0.f, ss = 0.f;
#pragma unroll
    for (int r = 0; r < 20; ++r) {
        float v = As[20 * a + r][o];
        mxv = fmaxf(mxv, v); mnv = fminf(mnv, v);
        s += v; ss = fmaf(v, v, ss);
    }
    int n = blockIdx.x * 4 + a;
    Mx[n * 64 + o] = mxv;
    Mn[n * 64 + o] = mnv;
    float* sred = &Ws[0][0];       // reuse Ws space (4*64 + 4*64)
    float* ssred = sred + 256;
    sred[a * 64 + o] = s;
    ssred[a * 64 + o] = ss;
    __syncthreads();
    if (tid < 64) {
        float ts = sred[tid] + sred[64 + tid] + sred[128 + tid] + sred[192 + tid];
        float tss = ssred[tid] + ssred[64 + tid] + ssred[128 + tid] + ssred[192 + tid];
        float* gg = gsOut + (blockIdx.x & (NREP - 1)) * 128;
        atomicAdd(gg + tid, ts);
        atomicAdd(gg + 64 + tid, tss);
    }
}

// ---------------------------------------------------------------- pool from Mx/Mn
__global__ __launch_bounds__(256) void pool_kernel(const float* __restrict__ Mx,
                                                   const float* __restrict__ Mn,
                                                   const float* __restrict__ gsIn,
                                                   const float* __restrict__ g,
                                                   const float* __restrict__ b,
                                                   float* __restrict__ Xout) {
    __shared__ float saff[128];
    int tid = threadIdx.x;
    compute_affine(gsIn, g, b, saff, tid);
    __syncthreads();
    int gid = blockIdx.x * 256 + tid;
    int o = gid & 63;
    float sc = saff[o], sh = saff[64 + o];
    float v = (sc >= 0.f) ? Mx[gid] : Mn[gid];
    Xout[gid] = lrelu(fmaf(v, sc, sh));
}

// ---------------------------------------------------------------- stage-3 fused edge+pool
__global__ __launch_bounds__(256) void zpool_kernel(const float* __restrict__ P,
                                                    const int* __restrict__ idx,
                                                    const float* __restrict__ gsIn,
                                                    const float* __restrict__ g,
                                                    const float* __restrict__ b,
                                                    float* __restrict__ Xout) {
    __shared__ float saff[128];
    int tid = threadIdx.x;
    compute_affine(gsIn, g, b, saff, tid);
    __syncthreads();
    int gid = blockIdx.x * 256 + tid;
    int n = gid >> 6, o = gid & 63;
    float An = P[n * 128 + o];
    float Bn = P[n * 128 + 64 + o];
    float base = Bn - An;
    float mxz = -INFINITY, mnz = INFINITY;
    for (int kk = 0; kk < KNN; ++kk) {
        int m = idx[n * KNN + kk];
        float z = P[m * 128 + o] + base;
        mxz = fmaxf(mxz, z); mnz = fminf(mnz, z);
    }
    float sc = saff[o], sh = saff[64 + o];
    float v = (sc >= 0.f) ? mxz : mnz;
    Xout[gid] = lrelu(fmaf(v, sc, sh));
}

// ---------------------------------------------------------------- fused final MLP: 8 points/block
__global__ __launch_bounds__(128) void mlp_kernel(const float* __restrict__ x1,
                                                  const float* __restrict__ x2,
                                                  const float* __restrict__ x3,
                                                  const float* __restrict__ W9at,
                                                  const float* __restrict__ b9a,
                                                  const float* __restrict__ W9bt,
                                                  const float* __restrict__ b9b,
                                                  float* __restrict__ out) {
    __shared__ float hs[8][128];
    int tid = threadIdx.x;  // 128
    int j = tid;
    int n0 = blockIdx.x * 8;
    float acc[8];
    float bj = b9a[j];
#pragma unroll
    for (int p = 0; p < 8; ++p) acc[p] = bj;
    for (int c = 0; c < 64; ++c) {
        float w = W9at[c * 128 + j];
#pragma unroll
        for (int p = 0; p < 8; ++p) acc[p] = fmaf(x1[(n0 + p) * 64 + c], w, acc[p]);
    }
    for (int c = 0; c < 64; ++c) {
        float w = W9at[(64 + c) * 128 + j];
#pragma unroll
        for (int p = 0; p < 8; ++p) acc[p] = fmaf(x2[(n0 + p) * 64 + c], w, acc[p]);
    }
    for (int c = 0; c < 64; ++c) {
        float w = W9at[(128 + c) * 128 + j];
#pragma unroll
        for (int p = 0; p < 8; ++p) acc[p] = fmaf(x3[(n0 + p) * 64 + c], w, acc[p]);
    }
#pragma unroll
    for (int p = 0; p < 8; ++p) hs[p][j] = fmaxf(acc[p], 0.f);
    __syncthreads();
    int p2 = tid >> 4, j2 = tid & 15;
    float a = b9b[j2];
    for (int c = 0; c < 128; ++c) a = fmaf(hs[p2][c], W9bt[c * 16 + j2], a);
    out[j2 * NPTS + n0 + p2] = a;
}

// ---------------------------------------------------------------- launch
extern "C" void kernel_launch(void* const* d_in, const int* in_sizes, int n_in,
                              void* d_out, int out_size, void* d_ws, size_t ws_size,
                              hipStream_t stream) {
    const float* x   = (const float*)d_in[0];
    const float* W1  = (const float*)d_in[2];
    const float* g1  = (const float*)d_in[3];
    const float* b1  = (const float*)d_in[4];
    const float* W2  = (const float*)d_in[5];
    const float* g2  = (const float*)d_in[6];
    const float* b2  = (const float*)d_in[7];
    const float* W3  = (const float*)d_in[8];
    const float* g3  = (const float*)d_in[9];
    const float* b3  = (const float*)d_in[10];
    const float* W4  = (const float*)d_in[11];
    const float* g4  = (const float*)d_in[12];
    const float* b4  = (const float*)d_in[13];
    const float* W5  = (const float*)d_in[14];
    const float* g5  = (const float*)d_in[15];
    const float* b5  = (const float*)d_in[16];
    const float* W9a = (const float*)d_in[17];
    const float* b9a = (const float*)d_in[18];
    const float* W9b = (const float*)d_in[19];
    const float* b9b = (const float*)d_in[20];
    float* out = (float*)d_out;

    char* ws = (char*)d_ws;
    int*    idx   = (int*)(ws + 0);                  // 655360
    float4* pk    = (float4*)(ws + 655360);          // 131072
    float*  P     = (float*)(ws + 786432);           // 4 MB
    float*  Mx    = (float*)(ws + 4980736);          // 2 MB
    float*  Mn    = (float*)(ws + 7077888);          // 2 MB
    float*  gsAll = (float*)(ws + 9175040);          // 20480
    float*  x1b   = (float*)(ws + 9195520);          // 2 MB
    float*  x2b   = (float*)(ws + 11292672);         // 2 MB
    float*  x3b   = (float*)(ws + 13389824);         // 2 MB
    float*  Wt1   = (float*)(ws + 15486976);         // 34304
    float*  Wt3   = (float*)(ws + 15521280);         // 32768
    float*  Wt5   = (float*)(ws + 15554048);         // 32768
    float*  W9at  = (float*)(ws + 15586816);         // 98304
    float*  W9bt  = (float*)(ws + 15685120);         // 8192
    (void)ws_size; (void)in_sizes; (void)n_in; (void)out_size;

    float* gs1 = gsAll;
    float* gs2 = gsAll + 1 * NREP * 128;
    float* gs3 = gsAll + 2 * NREP * 128;
    float* gs4 = gsAll + 3 * NREP * 128;
    float* gs5 = gsAll + 4 * NREP * 128;

    prep_kernel<<<254, 256, 0, stream>>>(x, W1, W3, W5, W9a, W9b, pk, Wt1, Wt3, Wt5, W9at, W9bt, gsAll);
    knn_kernel<<<NPTS / 16, 256, 0, stream>>>(pk, idx);

    // stage 1
    proj_kernel<<<NPTS / 8, 256, 0, stream>>>(x, 1, NPTS, 67, Wt1, P);
    zsum_kernel<<<512, 256, 0, stream>>>(P, idx, gs1);
    conv_gemm_kernel<<<NPTS * KNN / 80, 256, 0, stream>>>(P, idx, gs1, g1, b1, W2, gs2, Mx, Mn);
    pool_kernel<<<NPTS * 64 / 256, 256, 0, stream>>>(Mx, Mn, gs2, g2, b2, x1b);

    // stage 2
    proj_kernel<<<NPTS / 8, 256, 0, stream>>>(x1b, 64, 1, 64, Wt3, P);
    zsum_kernel<<<512, 256, 0, stream>>>(P, idx, gs3);
    conv_gemm_kernel<<<NPTS * KNN / 80, 256, 0, stream>>>(P, idx, gs3, g3, b3, W4, gs4, Mx, Mn);
    pool_kernel<<<NPTS * 64 / 256, 256, 0, stream>>>(Mx, Mn, gs4, g4, b4, x2b);

    // stage 3
    proj_kernel<<<NPTS / 8, 256, 0, stream>>>(x2b, 64, 1, 64, Wt5, P);
    zsum_kernel<<<512, 256, 0, stream>>>(P, idx, gs5);
    zpool_kernel<<<NPTS * 64 / 256, 256, 0, stream>>>(P, idx, gs5, g5, b5, x3b);

    // final MLP
    mlp_kernel<<<NPTS / 8, 128, 0, stream>>>(x1b, x2b, x3b, W9at, b9a, W9bt, b9b, out);
}

// Round 7
// 352.982 us; speedup vs baseline: 3.9432x; 1.1120x over previous
//
#include <hip/hip_runtime.h>

#define NPTS 8192
#define KNN  20
#define CHUNK 1024
#define CAP 128
#define NREP 8

__device__ __forceinline__ float pair_dist4(float qx, float qy, float qz, float xxn, float4 c) {
    float dot = fmaf(qz, c.z, fmaf(qy, c.y, qx * c.x));
    return fmaf(2.f, dot, -xxn) - c.w;
}
__device__ __forceinline__ float self_sq(float dx, float dy, float dz) {
    return fmaf(dz, dz, fmaf(dy, dy, dx * dx));
}
__device__ __forceinline__ float lrelu(float v) { return (v >= 0.f) ? v : 0.2f * v; }

// per-block BN affine from 8-replica global sums
__device__ __forceinline__ void compute_affine(const float* __restrict__ gs,
                                               const float* __restrict__ g,
                                               const float* __restrict__ b,
                                               float* saff, int tid) {
    if (tid < 64) {
        float s = 0.f, ss = 0.f;
#pragma unroll
        for (int r = 0; r < NREP; ++r) { s += gs[r * 128 + tid]; ss += gs[r * 128 + 64 + tid]; }
        const float invM = 1.f / (float)(NPTS * KNN);
        float mean = s * invM;
        float var = ss * invM - mean * mean;
        float sc = g[tid] * rsqrtf(var + 1e-5f);
        saff[tid] = sc;
        saff[64 + tid] = b[tid] - mean * sc;
    }
}

// ---------------------------------------------------------------- prep
__global__ __launch_bounds__(256) void prep_kernel(const float* __restrict__ x,
                                                   const float* __restrict__ W1,
                                                   const float* __restrict__ W3,
                                                   const float* __restrict__ W5,
                                                   const float* __restrict__ W9a,
                                                   const float* __restrict__ W9b,
                                                   float4* __restrict__ pk,
                                                   float* __restrict__ Wt1,
                                                   float* __restrict__ Wt3,
                                                   float* __restrict__ Wt5,
                                                   float* __restrict__ W9at,
                                                   float* __restrict__ W9bt,
                                                   float* __restrict__ gsAll) {
    int gid = blockIdx.x * 256 + threadIdx.x;
    if (gid < NPTS) {
        float dx = x[64 * NPTS + gid], dy = x[65 * NPTS + gid], dz = x[66 * NPTS + gid];
        pk[gid] = make_float4(dx, dy, dz, self_sq(dx, dy, dz));
        return;
    }
    gid -= NPTS;
    if (gid < 67 * 128) {
        int c = gid >> 7, o = gid & 127;
        Wt1[gid] = (o < 64) ? W1[o * 134 + c] : W1[(o - 64) * 134 + 67 + c];
        return;
    }
    gid -= 67 * 128;
    if (gid < 64 * 128) {
        int c = gid >> 7, o = gid & 127;
        Wt3[gid] = (o < 64) ? W3[o * 128 + c] : W3[(o - 64) * 128 + 64 + c];
        return;
    }
    gid -= 64 * 128;
    if (gid < 64 * 128) {
        int c = gid >> 7, o = gid & 127;
        Wt5[gid] = (o < 64) ? W5[o * 128 + c] : W5[(o - 64) * 128 + 64 + c];
        return;
    }
    gid -= 64 * 128;
    if (gid < 192 * 128) {
        int c = gid >> 7, j = gid & 127;
        W9at[gid] = W9a[j * 192 + c];
        return;
    }
    gid -= 192 * 128;
    if (gid < 128 * 16) {
        int c = gid >> 4, j = gid & 15;
        W9bt[gid] = W9b[j * 128 + c];
        return;
    }
    gid -= 128 * 16;
    if (gid < 5 * NREP * 128) gsAll[gid] = 0.f;
}

// ---------------------------------------------------------------- kNN: 1024 blocks, 2 q/wave
__global__ __launch_bounds__(256) void knn_kernel(const float4* __restrict__ pk,
                                                  int* __restrict__ idx_out) {
    __shared__ float4 cpt[CHUNK];
    __shared__ float bufv[8][CAP];
    __shared__ int   bufi[8][CAP];
    int tid = threadIdx.x, wid = tid >> 6, lane = tid & 63;
    int qbase = blockIdx.x * 8 + wid * 2;

    float qx[2], qy[2], qz[2], xxn[2], mv[2];
#pragma unroll
    for (int qi = 0; qi < 2; ++qi) {
        float4 qp = pk[qbase + qi];
        qx[qi] = qp.x; qy[qi] = qp.y; qz[qi] = qp.z; xxn[qi] = qp.w;
        mv[qi] = -INFINITY;
    }

    // pass 1: per-lane top-1 per query (disjoint 128-candidate set per lane)
    for (int ch = 0; ch < NPTS / CHUNK; ++ch) {
        __syncthreads();
        for (int i = tid; i < CHUNK; i += 256) cpt[i] = pk[ch * CHUNK + i];
        __syncthreads();
        for (int t = 0; t < CHUNK / 64; ++t) {
            float4 c = cpt[t * 64 + lane];
#pragma unroll
            for (int qi = 0; qi < 2; ++qi)
                mv[qi] = fmaxf(mv[qi], pair_dist4(qx[qi], qy[qi], qz[qi], xxn[qi], c));
        }
    }

    // theta per query: 20th largest of the 64 lane maxima (theta <= v20)
    float th[2];
#pragma unroll
    for (int qi = 0; qi < 2; ++qi) {
        float sel = mv[qi];
        float t = -INFINITY;
        for (int r = 0; r < KNN; ++r) {
            float v = sel;
#pragma unroll
            for (int m = 32; m >= 1; m >>= 1) v = fmaxf(v, __shfl_xor(v, m));
            t = v;
            unsigned long long bm = __ballot(sel == v);
            if (lane == __ffsll(bm) - 1) sel = -INFINITY;
        }
        th[qi] = t - 1e-3f;
    }

    // pass 2: compact survivors
    int wcnt[2] = {0, 0};
    for (int ch = 0; ch < NPTS / CHUNK; ++ch) {
        __syncthreads();
        for (int i = tid; i < CHUNK; i += 256) cpt[i] = pk[ch * CHUNK + i];
        __syncthreads();
        for (int t = 0; t < CHUNK / 64; ++t) {
            int gi = ch * CHUNK + t * 64 + lane;
            float4 c = cpt[t * 64 + lane];
#pragma unroll
            for (int qi = 0; qi < 2; ++qi) {
                float d = pair_dist4(qx[qi], qy[qi], qz[qi], xxn[qi], c);
                bool p = (d >= th[qi]);
                unsigned long long mk = __ballot(p);
                if (p) {
                    int pos = wcnt[qi] + __popcll(mk & ((1ull << lane) - 1));
                    if (pos < CAP) { bufv[wid * 2 + qi][pos] = d; bufi[wid * 2 + qi][pos] = gi; }
                }
                wcnt[qi] += (int)__popcll(mk);
            }
        }
    }

#pragma unroll 1
    for (int qi = 0; qi < 2; ++qi) {
        int q = qbase + qi;
        if (wcnt[qi] <= CAP) {
            float sv[2]; int si[2];
#pragma unroll
            for (int r = 0; r < 2; ++r) {
                int j = r * 64 + lane;
                bool ok = j < wcnt[qi];
                sv[r] = ok ? bufv[wid * 2 + qi][j] : -INFINITY;
                si[r] = ok ? bufi[wid * 2 + qi][j] : 0x7fffffff;
            }
            for (int r = 0; r < KNN; ++r) {
                float lv; int li; int ls;
                if (sv[0] > sv[1] || (sv[0] == sv[1] && si[0] < si[1])) { lv = sv[0]; li = si[0]; ls = 0; }
                else { lv = sv[1]; li = si[1]; ls = 1; }
                float wv = lv; int wi = li;
#pragma unroll
                for (int m = 32; m >= 1; m >>= 1) {
                    float ov = __shfl_xor(wv, m); int oi = __shfl_xor(wi, m);
                    if (ov > wv || (ov == wv && oi < wi)) { wv = ov; wi = oi; }
                }
                if (lv == wv && li == wi) {
                    if (ls == 0) { sv[0] = -INFINITY; si[0] = 0x7fffffff; }
                    else { sv[1] = -INFINITY; si[1] = 0x7fffffff; }
                }
                if (lane == 0) idx_out[q * KNN + r] = wi;
            }
        } else {
            float bv[KNN]; int bi[KNN];
#pragma unroll
            for (int j = 0; j < KNN; ++j) { bv[j] = -INFINITY; bi[j] = 0x7fffffff; }
            for (int t = 0; t < NPTS / 64; ++t) {
                int m = t * 64 + lane;
                float4 c = pk[m];
                float cv = pair_dist4(qx[qi], qy[qi], qz[qi], xxn[qi], c);
                int ci = m;
                if (cv > bv[KNN - 1] || (cv == bv[KNN - 1] && ci < bi[KNN - 1])) {
#pragma unroll
                    for (int j = 0; j < KNN; ++j) {
                        bool gsel = (cv > bv[j]) || (cv == bv[j] && ci < bi[j]);
                        float tv = bv[j]; int ti = bi[j];
                        if (gsel) { bv[j] = cv; bi[j] = ci; cv = tv; ci = ti; }
                    }
                }
            }
            for (int r = 0; r < KNN; ++r) {
                float wv = bv[0]; int wi = bi[0];
#pragma unroll
                for (int m = 32; m >= 1; m >>= 1) {
                    float ov = __shfl_xor(wv, m); int oi = __shfl_xor(wi, m);
                    if (ov > wv || (ov == wv && oi < wi)) { wv = ov; wi = oi; }
                }
                if (bv[0] == wv && bi[0] == wi) {
#pragma unroll
                    for (int j = 0; j < KNN - 1; ++j) { bv[j] = bv[j + 1]; bi[j] = bi[j + 1]; }
                    bv[KNN - 1] = -INFINITY; bi[KNN - 1] = 0x7fffffff;
                }
                if (lane == 0) idx_out[q * KNN + r] = wi;
            }
        }
    }
}

// ---------------------------------------------------------------- projection: 8 points/block
__global__ __launch_bounds__(256) void proj_kernel(const float* __restrict__ X,
                                                   int sn, int sc, int Cin,
                                                   const float* __restrict__ Wt,
                                                   float* __restrict__ P) {
    int tid = threadIdx.x;
    int o = tid & 127;
    int h = tid >> 7;  // 0..1
    int n0 = blockIdx.x * 8 + h * 4;
    float acc[4] = {0.f, 0.f, 0.f, 0.f};
    for (int c = 0; c < Cin; ++c) {
        float w = Wt[c * 128 + o];
#pragma unroll
        for (int i = 0; i < 4; ++i) acc[i] = fmaf(X[(n0 + i) * sn + c * sc], w, acc[i]);
    }
#pragma unroll
    for (int i = 0; i < 4; ++i) P[(n0 + i) * 128 + o] = acc[i];
}

// ---------------------------------------------------------------- z stats (gather, atomic sums)
__global__ __launch_bounds__(256) void zsum_kernel(const float* __restrict__ P,
                                                   const int* __restrict__ idx,
                                                   float* __restrict__ gs) {
    int tid = threadIdx.x;
    int o = tid & 63;
    float sum = 0.f, sumsq = 0.f;
    int n0 = blockIdx.x * 4;
    for (int ni = 0; ni < 4; ++ni) {
        int n = n0 + ni;
        float An = P[n * 128 + o];
        float Bn = P[n * 128 + 64 + o];
        float base = Bn - An;
        for (int kk = tid >> 6; kk < KNN; kk += 4) {
            int m = idx[n * KNN + kk];
            float z = P[m * 128 + o] + base;
            sum += z;
            sumsq = fmaf(z, z, sumsq);
        }
    }
    __shared__ float s1[256], s2[256];
    s1[tid] = sum; s2[tid] = sumsq;
    __syncthreads();
    if (tid < 64) {
        float a = s1[tid] + s1[tid + 64] + s1[tid + 128] + s1[tid + 192];
        float b = s2[tid] + s2[tid + 64] + s2[tid + 128] + s2[tid + 192];
        float* g = gs + (blockIdx.x & (NREP - 1)) * 128;
        atomicAdd(g + tid, a);
        atomicAdd(g + 64 + tid, b);
    }
}

// ---------------------------------------------------------------- conv GEMM: 80-row n-aligned tile
__global__ __launch_bounds__(256) void conv_gemm_kernel(const float* __restrict__ P,
                                                        const int* __restrict__ idx,
                                                        const float* __restrict__ gsIn,
                                                        const float* __restrict__ gIn,
                                                        const float* __restrict__ bIn,
                                                        const float* __restrict__ W,
                                                        float* __restrict__ gsOut,
                                                        float* __restrict__ Mx,
                                                        float* __restrict__ Mn) {
    __shared__ float As[80][68];
    __shared__ float Ws[64][68];
    __shared__ float saff[128];
    int tid = threadIdx.x;
    int r0 = blockIdx.x * 80;

    compute_affine(gsIn, gIn, bIn, saff, tid);
    for (int i2 = tid; i2 < 1024; i2 += 256) {
        int rr = i2 >> 4, c4 = (i2 & 15) * 4;
        *(float4*)&Ws[rr][c4] = *(const float4*)&W[rr * 64 + c4];
    }
    __syncthreads();

    for (int i2 = tid; i2 < 1280; i2 += 256) {
        int rr = i2 >> 4, c4 = (i2 & 15) * 4;
        int grow = r0 + rr;
        int n = grow / 20;
        int m = idx[grow];
        float4 zn = *(const float4*)&P[(size_t)m * 128 + c4];
        float4 an = *(const float4*)&P[(size_t)n * 128 + c4];
        float4 bn = *(const float4*)&P[(size_t)n * 128 + 64 + c4];
        float4 ov; float z;
        z = zn.x + (bn.x - an.x); ov.x = lrelu(fmaf(z, saff[c4 + 0], saff[64 + c4 + 0]));
        z = zn.y + (bn.y - an.y); ov.y = lrelu(fmaf(z, saff[c4 + 1], saff[64 + c4 + 1]));
        z = zn.z + (bn.z - an.z); ov.z = lrelu(fmaf(z, saff[c4 + 2], saff[64 + c4 + 2]));
        z = zn.w + (bn.w - an.w); ov.w = lrelu(fmaf(z, saff[c4 + 3], saff[64 + c4 + 3]));
        *(float4*)&As[rr][c4] = ov;
    }
    __syncthreads();

    int ty = tid >> 4, tx = tid & 15;
    float acc[5][4];
#pragma unroll
    for (int i = 0; i < 5; ++i)
#pragma unroll
        for (int j = 0; j < 4; ++j) acc[i][j] = 0.f;

    for (int c4 = 0; c4 < 64; c4 += 4) {
        float4 a4[5], w4[4];
#pragma unroll
        for (int i = 0; i < 5; ++i) a4[i] = *(const float4*)&As[ty + 16 * i][c4];
#pragma unroll
        for (int j = 0; j < 4; ++j) w4[j] = *(const float4*)&Ws[tx + 16 * j][c4];
#pragma unroll
        for (int i = 0; i < 5; ++i)
#pragma unroll
            for (int j = 0; j < 4; ++j) {
                acc[i][j] = fmaf(a4[i].x, w4[j].x, acc[i][j]);
                acc[i][j] = fmaf(a4[i].y, w4[j].y, acc[i][j]);
                acc[i][j] = fmaf(a4[i].z, w4[j].z, acc[i][j]);
                acc[i][j] = fmaf(a4[i].w, w4[j].w, acc[i][j]);
            }
    }
    __syncthreads();

#pragma unroll
    for (int i = 0; i < 5; ++i)
#pragma unroll
        for (int j = 0; j < 4; ++j) As[ty + 16 * i][tx + 16 * j] = acc[i][j];
    __syncthreads();

    int a = tid >> 6, o = tid & 63;
    float mxv = -INFINITY, mnv = INFINITY, s = 0.f, ss = 0.f;
#pragma unroll
    for (int r = 0; r < 20; ++r) {
        float v = As[20 * a + r][o];
        mxv = fmaxf(mxv, v); mnv = fminf(mnv, v);
        s += v; ss = fmaf(v, v, ss);
    }
    int n = blockIdx.x * 4 + a;
    Mx[n * 64 + o] = mxv;
    Mn[n * 64 + o] = mnv;
    float* sred = &Ws[0][0];
    float* ssred = sred + 256;
    sred[a * 64 + o] = s;
    ssred[a * 64 + o] = ss;
    __syncthreads();
    if (tid < 64) {
        float ts = sred[tid] + sred[64 + tid] + sred[128 + tid] + sred[192 + tid];
        float tss = ssred[tid] + ssred[64 + tid] + ssred[128 + tid] + ssred[192 + tid];
        float* gg = gsOut + (blockIdx.x & (NREP - 1)) * 128;
        atomicAdd(gg + tid, ts);
        atomicAdd(gg + 64 + tid, tss);
    }
}

// ---------------------------------------------------------------- pool from Mx/Mn
__global__ __launch_bounds__(256) void pool_kernel(const float* __restrict__ Mx,
                                                   const float* __restrict__ Mn,
                                                   const float* __restrict__ gsIn,
                                                   const float* __restrict__ g,
                                                   const float* __restrict__ b,
                                                   float* __restrict__ Xout) {
    __shared__ float saff[128];
    int tid = threadIdx.x;
    compute_affine(gsIn, g, b, saff, tid);
    __syncthreads();
    int gid = blockIdx.x * 256 + tid;
    int o = gid & 63;
    float sc = saff[o], sh = saff[64 + o];
    float v = (sc >= 0.f) ? Mx[gid] : Mn[gid];
    Xout[gid] = lrelu(fmaf(v, sc, sh));
}

// ---------------------------------------------------------------- stage-3 fused edge+pool
__global__ __launch_bounds__(256) void zpool_kernel(const float* __restrict__ P,
                                                    const int* __restrict__ idx,
                                                    const float* __restrict__ gsIn,
                                                    const float* __restrict__ g,
                                                    const float* __restrict__ b,
                                                    float* __restrict__ Xout) {
    __shared__ float saff[128];
    int tid = threadIdx.x;
    compute_affine(gsIn, g, b, saff, tid);
    __syncthreads();
    int gid = blockIdx.x * 256 + tid;
    int n = gid >> 6, o = gid & 63;
    float An = P[n * 128 + o];
    float Bn = P[n * 128 + 64 + o];
    float base = Bn - An;
    float mxz = -INFINITY, mnz = INFINITY;
    for (int kk = 0; kk < KNN; ++kk) {
        int m = idx[n * KNN + kk];
        float z = P[m * 128 + o] + base;
        mxz = fmaxf(mxz, z); mnz = fminf(mnz, z);
    }
    float sc = saff[o], sh = saff[64 + o];
    float v = (sc >= 0.f) ? mxz : mnz;
    Xout[gid] = lrelu(fmaf(v, sc, sh));
}

// ---------------------------------------------------------------- fused final MLP: 8 points/block
__global__ __launch_bounds__(128) void mlp_kernel(const float* __restrict__ x1,
                                                  const float* __restrict__ x2,
                                                  const float* __restrict__ x3,
                                                  const float* __restrict__ W9at,
                                                  const float* __restrict__ b9a,
                                                  const float* __restrict__ W9bt,
                                                  const float* __restrict__ b9b,
                                                  float* __restrict__ out) {
    __shared__ float hs[8][128];
    int tid = threadIdx.x;  // 128
    int j = tid;
    int n0 = blockIdx.x * 8;
    float acc[8];
    float bj = b9a[j];
#pragma unroll
    for (int p = 0; p < 8; ++p) acc[p] = bj;
    for (int c = 0; c < 64; ++c) {
        float w = W9at[c * 128 + j];
#pragma unroll
        for (int p = 0; p < 8; ++p) acc[p] = fmaf(x1[(n0 + p) * 64 + c], w, acc[p]);
    }
    for (int c = 0; c < 64; ++c) {
        float w = W9at[(64 + c) * 128 + j];
#pragma unroll
        for (int p = 0; p < 8; ++p) acc[p] = fmaf(x2[(n0 + p) * 64 + c], w, acc[p]);
    }
    for (int c = 0; c < 64; ++c) {
        float w = W9at[(128 + c) * 128 + j];
#pragma unroll
        for (int p = 0; p < 8; ++p) acc[p] = fmaf(x3[(n0 + p) * 64 + c], w, acc[p]);
    }
#pragma unroll
    for (int p = 0; p < 8; ++p) hs[p][j] = fmaxf(acc[p], 0.f);
    __syncthreads();
    int p2 = tid >> 4, j2 = tid & 15;
    float a = b9b[j2];
    for (int c = 0; c < 128; ++c) a = fmaf(hs[p2][c], W9bt[c * 16 + j2], a);
    out[j2 * NPTS + n0 + p2] = a;
}

// ---------------------------------------------------------------- launch
extern "C" void kernel_launch(void* const* d_in, const int* in_sizes, int n_in,
                              void* d_out, int out_size, void* d_ws, size_t ws_size,
                              hipStream_t stream) {
    const float* x   = (const float*)d_in[0];
    const float* W1  = (const float*)d_in[2];
    const float* g1  = (const float*)d_in[3];
    const float* b1  = (const float*)d_in[4];
    const float* W2  = (const float*)d_in[5];
    const float* g2  = (const float*)d_in[6];
    const float* b2  = (const float*)d_in[7];
    const float* W3  = (const float*)d_in[8];
    const float* g3  = (const float*)d_in[9];
    const float* b3  = (const float*)d_in[10];
    const float* W4  = (const float*)d_in[11];
    const float* g4  = (const float*)d_in[12];
    const float* b4  = (const float*)d_in[13];
    const float* W5  = (const float*)d_in[14];
    const float* g5  = (const float*)d_in[15];
    const float* b5  = (const float*)d_in[16];
    const float* W9a = (const float*)d_in[17];
    const float* b9a = (const float*)d_in[18];
    const float* W9b = (const float*)d_in[19];
    const float* b9b = (const float*)d_in[20];
    float* out = (float*)d_out;

    char* ws = (char*)d_ws;
    int*    idx   = (int*)(ws + 0);                  // 655360
    float4* pk    = (float4*)(ws + 655360);          // 131072
    float*  P     = (float*)(ws + 786432);           // 4 MB
    float*  Mx    = (float*)(ws + 4980736);          // 2 MB
    float*  Mn    = (float*)(ws + 7077888);          // 2 MB
    float*  gsAll = (float*)(ws + 9175040);          // 20480
    float*  x1b   = (float*)(ws + 9195520);          // 2 MB
    float*  x2b   = (float*)(ws + 11292672);         // 2 MB
    float*  x3b   = (float*)(ws + 13389824);         // 2 MB
    float*  Wt1   = (float*)(ws + 15486976);         // 34304
    float*  Wt3   = (float*)(ws + 15521280);         // 32768
    float*  Wt5   = (float*)(ws + 15554048);         // 32768
    float*  W9at  = (float*)(ws + 15586816);         // 98304
    float*  W9bt  = (float*)(ws + 15685120);         // 8192
    (void)ws_size; (void)in_sizes; (void)n_in; (void)out_size;

    float* gs1 = gsAll;
    float* gs2 = gsAll + 1 * NREP * 128;
    float* gs3 = gsAll + 2 * NREP * 128;
    float* gs4 = gsAll + 3 * NREP * 128;
    float* gs5 = gsAll + 4 * NREP * 128;

    prep_kernel<<<254, 256, 0, stream>>>(x, W1, W3, W5, W9a, W9b, pk, Wt1, Wt3, Wt5, W9at, W9bt, gsAll);
    knn_kernel<<<NPTS / 8, 256, 0, stream>>>(pk, idx);

    // stage 1
    proj_kernel<<<NPTS / 8, 256, 0, stream>>>(x, 1, NPTS, 67, Wt1, P);
    zsum_kernel<<<NPTS / 4, 256, 0, stream>>>(P, idx, gs1);
    conv_gemm_kernel<<<NPTS * KNN / 80, 256, 0, stream>>>(P, idx, gs1, g1, b1, W2, gs2, Mx, Mn);
    pool_kernel<<<NPTS * 64 / 256, 256, 0, stream>>>(Mx, Mn, gs2, g2, b2, x1b);

    // stage 2
    proj_kernel<<<NPTS / 8, 256, 0, stream>>>(x1b, 64, 1, 64, Wt3, P);
    zsum_kernel<<<NPTS / 4, 256, 0, stream>>>(P, idx, gs3);
    conv_gemm_kernel<<<NPTS * KNN / 80, 256, 0, stream>>>(P, idx, gs3, g3, b3, W4, gs4, Mx, Mn);
    pool_kernel<<<NPTS * 64 / 256, 256, 0, stream>>>(Mx, Mn, gs4, g4, b4, x2b);

    // stage 3
    proj_kernel<<<NPTS / 8, 256, 0, stream>>>(x2b, 64, 1, 64, Wt5, P);
    zsum_kernel<<<NPTS / 4, 256, 0, stream>>>(P, idx, gs5);
    zpool_kernel<<<NPTS * 64 / 256, 256, 0, stream>>>(P, idx, gs5, g5, b5, x3b);

    // final MLP
    mlp_kernel<<<NPTS / 8, 128, 0, stream>>>(x1b, x2b, x3b, W9at, b9a, W9bt, b9b, out);
}

// Round 8
// 322.357 us; speedup vs baseline: 4.3178x; 1.0950x over previous
//
#include <hip/hip_runtime.h>

#define NPTS 8192
#define KNN  20
#define NREP 8
#define NSLICE 8
#define SLICE 1024
#define CAP 192

__device__ __forceinline__ float pair_dist4(float qx, float qy, float qz, float xxn, float4 c) {
    float dot = fmaf(qz, c.z, fmaf(qy, c.y, qx * c.x));
    return fmaf(2.f, dot, -xxn) - c.w;
}
__device__ __forceinline__ float self_sq(float dx, float dy, float dz) {
    return fmaf(dz, dz, fmaf(dy, dy, dx * dx));
}
__device__ __forceinline__ float lrelu(float v) { return (v >= 0.f) ? v : 0.2f * v; }

__device__ __forceinline__ void compute_affine(const float* __restrict__ gs,
                                               const float* __restrict__ g,
                                               const float* __restrict__ b,
                                               float* saff, int tid) {
    if (tid < 64) {
        float s = 0.f, ss = 0.f;
#pragma unroll
        for (int r = 0; r < NREP; ++r) { s += gs[r * 128 + tid]; ss += gs[r * 128 + 64 + tid]; }
        const float invM = 1.f / (float)(NPTS * KNN);
        float mean = s * invM;
        float var = ss * invM - mean * mean;
        float sc = g[tid] * rsqrtf(var + 1e-5f);
        saff[tid] = sc;
        saff[64 + tid] = b[tid] - mean * sc;
    }
}

// ---------------------------------------------------------------- prep (also zeroes gsAll + scount)
__global__ __launch_bounds__(256) void prep_kernel(const float* __restrict__ x,
                                                   const float* __restrict__ W1,
                                                   const float* __restrict__ W3,
                                                   const float* __restrict__ W5,
                                                   const float* __restrict__ W9a,
                                                   const float* __restrict__ W9b,
                                                   float4* __restrict__ pk,
                                                   float* __restrict__ Wt1,
                                                   float* __restrict__ Wt3,
                                                   float* __restrict__ Wt5,
                                                   float* __restrict__ W9at,
                                                   float* __restrict__ W9bt,
                                                   float* __restrict__ gsAll,
                                                   int* __restrict__ scount) {
    int gid = blockIdx.x * 256 + threadIdx.x;
    if (gid < NPTS) {
        float dx = x[64 * NPTS + gid], dy = x[65 * NPTS + gid], dz = x[66 * NPTS + gid];
        pk[gid] = make_float4(dx, dy, dz, self_sq(dx, dy, dz));
        return;
    }
    gid -= NPTS;
    if (gid < 67 * 128) {
        int c = gid >> 7, o = gid & 127;
        Wt1[gid] = (o < 64) ? W1[o * 134 + c] : W1[(o - 64) * 134 + 67 + c];
        return;
    }
    gid -= 67 * 128;
    if (gid < 64 * 128) {
        int c = gid >> 7, o = gid & 127;
        Wt3[gid] = (o < 64) ? W3[o * 128 + c] : W3[(o - 64) * 128 + 64 + c];
        return;
    }
    gid -= 64 * 128;
    if (gid < 64 * 128) {
        int c = gid >> 7, o = gid & 127;
        Wt5[gid] = (o < 64) ? W5[o * 128 + c] : W5[(o - 64) * 128 + 64 + c];
        return;
    }
    gid -= 64 * 128;
    if (gid < 192 * 128) {
        int c = gid >> 7, j = gid & 127;
        W9at[gid] = W9a[j * 192 + c];
        return;
    }
    gid -= 192 * 128;
    if (gid < 128 * 16) {
        int c = gid >> 4, j = gid & 15;
        W9bt[gid] = W9b[j * 128 + c];
        return;
    }
    gid -= 128 * 16;
    if (gid < 5 * NREP * 128) { gsAll[gid] = 0.f; return; }
    gid -= 5 * NREP * 128;
    if (gid < NPTS) scount[gid] = 0;
}

// ---------------------------------------------------------------- kNN K1: per-(q,lane,slice) champions
__global__ __launch_bounds__(256) void knn_champ(const float4* __restrict__ pk,
                                                 float* __restrict__ champ) {
    __shared__ float4 cpt[SLICE];
    int tid = threadIdx.x, wid = tid >> 6, lane = tid & 63;
    int qg = blockIdx.x >> 3;
    int s  = blockIdx.x & 7;
    for (int i = tid; i < SLICE; i += 256) cpt[i] = pk[s * SLICE + i];
    int qbase = qg * 16 + wid * 4;
    float qx[4], qy[4], qz[4], xxn[4], mv[4];
#pragma unroll
    for (int qi = 0; qi < 4; ++qi) {
        float4 qp = pk[qbase + qi];
        qx[qi] = qp.x; qy[qi] = qp.y; qz[qi] = qp.z; xxn[qi] = qp.w;
        mv[qi] = -INFINITY;
    }
    __syncthreads();
    for (int t = 0; t < SLICE / 64; ++t) {
        float4 c = cpt[t * 64 + lane];
#pragma unroll
        for (int qi = 0; qi < 4; ++qi)
            mv[qi] = fmaxf(mv[qi], pair_dist4(qx[qi], qy[qi], qz[qi], xxn[qi], c));
    }
#pragma unroll
    for (int qi = 0; qi < 4; ++qi)
        champ[(qbase + qi) * 512 + s * 64 + lane] = mv[qi];
}

// ---------------------------------------------------------------- kNN K2: theta = 20th largest champion
__global__ __launch_bounds__(256) void knn_theta(const float* __restrict__ champ,
                                                 float* __restrict__ theta) {
    int tid = threadIdx.x, wid = tid >> 6, lane = tid & 63;
    int q = blockIdx.x * 4 + wid;
    float ch[8];
#pragma unroll
    for (int r = 0; r < 8; ++r) ch[r] = champ[q * 512 + r * 64 + lane];
    float th = -INFINITY;
    for (int r = 0; r < KNN; ++r) {
        float lm = ch[0];
#pragma unroll
        for (int j = 1; j < 8; ++j) lm = fmaxf(lm, ch[j]);
        float v = lm;
#pragma unroll
        for (int m = 32; m >= 1; m >>= 1) v = fmaxf(v, __shfl_xor(v, m));
        th = v;
        unsigned long long bm = __ballot(lm == v);
        if (lane == __ffsll(bm) - 1) {
            bool done = false;
#pragma unroll
            for (int j = 0; j < 8; ++j)
                if (!done && ch[j] == v) { ch[j] = -INFINITY; done = true; }
        }
    }
    if (lane == 0) theta[q] = th - 1e-3f;
}

// ---------------------------------------------------------------- kNN K3: filter + compact survivors
__global__ __launch_bounds__(256) void knn_filter(const float4* __restrict__ pk,
                                                  const float* __restrict__ theta,
                                                  int* __restrict__ scount,
                                                  int2* __restrict__ surv) {
    __shared__ float4 cpt[SLICE];
    int tid = threadIdx.x, wid = tid >> 6, lane = tid & 63;
    int qg = blockIdx.x >> 3;
    int s  = blockIdx.x & 7;
    for (int i = tid; i < SLICE; i += 256) cpt[i] = pk[s * SLICE + i];
    int qbase = qg * 16 + wid * 4;
    float qx[4], qy[4], qz[4], xxn[4], th[4];
#pragma unroll
    for (int qi = 0; qi < 4; ++qi) {
        float4 qp = pk[qbase + qi];
        qx[qi] = qp.x; qy[qi] = qp.y; qz[qi] = qp.z; xxn[qi] = qp.w;
        th[qi] = theta[qbase + qi];
    }
    __syncthreads();
    for (int t = 0; t < SLICE / 64; ++t) {
        int gi = s * SLICE + t * 64 + lane;
        float4 c = cpt[t * 64 + lane];
#pragma unroll
        for (int qi = 0; qi < 4; ++qi) {
            float d = pair_dist4(qx[qi], qy[qi], qz[qi], xxn[qi], c);
            bool p = (d >= th[qi]);
            unsigned long long mk = __ballot(p);
            if (mk) {
                int q = qbase + qi;
                int src = __ffsll(mk) - 1;
                int base = 0;
                if (lane == src) base = atomicAdd(&scount[q], (int)__popcll(mk));
                base = __shfl(base, src);
                if (p) {
                    int pos = base + (int)__popcll(mk & ((1ull << lane) - 1));
                    if (pos < CAP) surv[q * CAP + pos] = make_int2(__float_as_int(d), gi);
                }
            }
        }
    }
}

// ---------------------------------------------------------------- kNN K4: exact top-20 selection
__global__ __launch_bounds__(256) void knn_select(const float4* __restrict__ pk,
                                                  const int* __restrict__ scount,
                                                  const int2* __restrict__ surv,
                                                  int* __restrict__ idx_out) {
    int tid = threadIdx.x, wid = tid >> 6, lane = tid & 63;
    int q = blockIdx.x * 4 + wid;
    int cnt = scount[q];
    if (cnt <= CAP) {
        float sv[3]; int si[3];
#pragma unroll
        for (int r = 0; r < 3; ++r) {
            int j = r * 64 + lane;
            bool ok = j < cnt;
            int2 pr = ok ? surv[q * CAP + j] : make_int2(0, 0);
            sv[r] = ok ? __int_as_float(pr.x) : -INFINITY;
            si[r] = ok ? pr.y : 0x7fffffff;
        }
        for (int r = 0; r < KNN; ++r) {
            float lv = -INFINITY; int li = 0x7fffffff; int ls = -1;
#pragma unroll
            for (int s3 = 0; s3 < 3; ++s3) {
                bool g = (sv[s3] > lv) || (sv[s3] == lv && si[s3] < li);
                if (g) { lv = sv[s3]; li = si[s3]; ls = s3; }
            }
            float wv = lv; int wi = li;
#pragma unroll
            for (int m = 32; m >= 1; m >>= 1) {
                float ov = __shfl_xor(wv, m); int oi = __shfl_xor(wi, m);
                if (ov > wv || (ov == wv && oi < wi)) { wv = ov; wi = oi; }
            }
            if (lv == wv && li == wi) {
#pragma unroll
                for (int s3 = 0; s3 < 3; ++s3)
                    if (s3 == ls) { sv[s3] = -INFINITY; si[s3] = 0x7fffffff; }
            }
            if (lane == 0) idx_out[q * KNN + r] = wi;
        }
    } else {
        // exact fallback: 20-round lex-max scan over all points (never in practice)
        float4 qp = pk[q];
        float qx = qp.x, qy = qp.y, qz = qp.z, xxn = qp.w;
        float pv = INFINITY; int pi = -1;
        for (int r = 0; r < KNN; ++r) {
            float bv = -INFINITY; int bi = 0x7fffffff;
            for (int t = 0; t < NPTS / 64; ++t) {
                int i = t * 64 + lane;
                float d = pair_dist4(qx, qy, qz, xxn, pk[i]);
                bool adm = (d < pv) || (d == pv && i > pi);
                if (adm && (d > bv || (d == bv && i < bi))) { bv = d; bi = i; }
            }
            float wv = bv; int wi = bi;
#pragma unroll
            for (int m = 32; m >= 1; m >>= 1) {
                float ov = __shfl_xor(wv, m); int oi = __shfl_xor(wi, m);
                if (ov > wv || (ov == wv && oi < wi)) { wv = ov; wi = oi; }
            }
            if (lane == 0) idx_out[q * KNN + r] = wi;
            pv = wv; pi = wi;
        }
    }
}

// ---------------------------------------------------------------- projection: 8 points/block
__global__ __launch_bounds__(256) void proj_kernel(const float* __restrict__ X,
                                                   int sn, int sc, int Cin,
                                                   const float* __restrict__ Wt,
                                                   float* __restrict__ P) {
    int tid = threadIdx.x;
    int o = tid & 127;
    int h = tid >> 7;
    int n0 = blockIdx.x * 8 + h * 4;
    float acc[4] = {0.f, 0.f, 0.f, 0.f};
    for (int c = 0; c < Cin; ++c) {
        float w = Wt[c * 128 + o];
#pragma unroll
        for (int i = 0; i < 4; ++i) acc[i] = fmaf(X[(n0 + i) * sn + c * sc], w, acc[i]);
    }
#pragma unroll
    for (int i = 0; i < 4; ++i) P[(n0 + i) * 128 + o] = acc[i];
}

// ---------------------------------------------------------------- z stats (gather, atomic sums)
__global__ __launch_bounds__(256) void zsum_kernel(const float* __restrict__ P,
                                                   const int* __restrict__ idx,
                                                   float* __restrict__ gs) {
    int tid = threadIdx.x;
    int o = tid & 63;
    float sum = 0.f, sumsq = 0.f;
    int n0 = blockIdx.x * 4;
    for (int ni = 0; ni < 4; ++ni) {
        int n = n0 + ni;
        float An = P[n * 128 + o];
        float Bn = P[n * 128 + 64 + o];
        float base = Bn - An;
        for (int kk = tid >> 6; kk < KNN; kk += 4) {
            int m = idx[n * KNN + kk];
            float z = P[m * 128 + o] + base;
            sum += z;
            sumsq = fmaf(z, z, sumsq);
        }
    }
    __shared__ float s1[256], s2[256];
    s1[tid] = sum; s2[tid] = sumsq;
    __syncthreads();
    if (tid < 64) {
        float a = s1[tid] + s1[tid + 64] + s1[tid + 128] + s1[tid + 192];
        float b = s2[tid] + s2[tid + 64] + s2[tid + 128] + s2[tid + 192];
        float* g = gs + (blockIdx.x & (NREP - 1)) * 128;
        atomicAdd(g + tid, a);
        atomicAdd(g + 64 + tid, b);
    }
}

// ---------------------------------------------------------------- conv GEMM: 80-row n-aligned tile
__global__ __launch_bounds__(256) void conv_gemm_kernel(const float* __restrict__ P,
                                                        const int* __restrict__ idx,
                                                        const float* __restrict__ gsIn,
                                                        const float* __restrict__ gIn,
                                                        const float* __restrict__ bIn,
                                                        const float* __restrict__ W,
                                                        float* __restrict__ gsOut,
                                                        float* __restrict__ Mx,
                                                        float* __restrict__ Mn) {
    __shared__ float As[80][68];
    __shared__ float Ws[64][68];
    __shared__ float saff[128];
    int tid = threadIdx.x;
    int r0 = blockIdx.x * 80;

    compute_affine(gsIn, gIn, bIn, saff, tid);
    for (int i2 = tid; i2 < 1024; i2 += 256) {
        int rr = i2 >> 4, c4 = (i2 & 15) * 4;
        *(float4*)&Ws[rr][c4] = *(const float4*)&W[rr * 64 + c4];
    }
    __syncthreads();

    for (int i2 = tid; i2 < 1280; i2 += 256) {
        int rr = i2 >> 4, c4 = (i2 & 15) * 4;
        int grow = r0 + rr;
        int n = grow / 20;
        int m = idx[grow];
        float4 zn = *(const float4*)&P[(size_t)m * 128 + c4];
        float4 an = *(const float4*)&P[(size_t)n * 128 + c4];
        float4 bn = *(const float4*)&P[(size_t)n * 128 + 64 + c4];
        float4 ov; float z;
        z = zn.x + (bn.x - an.x); ov.x = lrelu(fmaf(z, saff[c4 + 0], saff[64 + c4 + 0]));
        z = zn.y + (bn.y - an.y); ov.y = lrelu(fmaf(z, saff[c4 + 1], saff[64 + c4 + 1]));
        z = zn.z + (bn.z - an.z); ov.z = lrelu(fmaf(z, saff[c4 + 2], saff[64 + c4 + 2]));
        z = zn.w + (bn.w - an.w); ov.w = lrelu(fmaf(z, saff[c4 + 3], saff[64 + c4 + 3]));
        *(float4*)&As[rr][c4] = ov;
    }
    __syncthreads();

    int ty = tid >> 4, tx = tid & 15;
    float acc[5][4];
#pragma unroll
    for (int i = 0; i < 5; ++i)
#pragma unroll
        for (int j = 0; j < 4; ++j) acc[i][j] = 0.f;

    for (int c4 = 0; c4 < 64; c4 += 4) {
        float4 a4[5], w4[4];
#pragma unroll
        for (int i = 0; i < 5; ++i) a4[i] = *(const float4*)&As[ty + 16 * i][c4];
#pragma unroll
        for (int j = 0; j < 4; ++j) w4[j] = *(const float4*)&Ws[tx + 16 * j][c4];
#pragma unroll
        for (int i = 0; i < 5; ++i)
#pragma unroll
            for (int j = 0; j < 4; ++j) {
                acc[i][j] = fmaf(a4[i].x, w4[j].x, acc[i][j]);
                acc[i][j] = fmaf(a4[i].y, w4[j].y, acc[i][j]);
                acc[i][j] = fmaf(a4[i].z, w4[j].z, acc[i][j]);
                acc[i][j] = fmaf(a4[i].w, w4[j].w, acc[i][j]);
            }
    }
    __syncthreads();

#pragma unroll
    for (int i = 0; i < 5; ++i)
#pragma unroll
        for (int j = 0; j < 4; ++j) As[ty + 16 * i][tx + 16 * j] = acc[i][j];
    __syncthreads();

    int a = tid >> 6, o = tid & 63;
    float mxv = -INFINITY, mnv = INFINITY, s = 0.f, ss = 0.f;
#pragma unroll
    for (int r = 0; r < 20; ++r) {
        float v = As[20 * a + r][o];
        mxv = fmaxf(mxv, v); mnv = fminf(mnv, v);
        s += v; ss = fmaf(v, v, ss);
    }
    int n = blockIdx.x * 4 + a;
    Mx[n * 64 + o] = mxv;
    Mn[n * 64 + o] = mnv;
    float* sred = &Ws[0][0];
    float* ssred = sred + 256;
    sred[a * 64 + o] = s;
    ssred[a * 64 + o] = ss;
    __syncthreads();
    if (tid < 64) {
        float ts = sred[tid] + sred[64 + tid] + sred[128 + tid] + sred[192 + tid];
        float tss = ssred[tid] + ssred[64 + tid] + ssred[128 + tid] + ssred[192 + tid];
        float* gg = gsOut + (blockIdx.x & (NREP - 1)) * 128;
        atomicAdd(gg + tid, ts);
        atomicAdd(gg + 64 + tid, tss);
    }
}

// ---------------------------------------------------------------- pool from Mx/Mn
__global__ __launch_bounds__(256) void pool_kernel(const float* __restrict__ Mx,
                                                   const float* __restrict__ Mn,
                                                   const float* __restrict__ gsIn,
                                                   const float* __restrict__ g,
                                                   const float* __restrict__ b,
                                                   float* __restrict__ Xout) {
    __shared__ float saff[128];
    int tid = threadIdx.x;
    compute_affine(gsIn, g, b, saff, tid);
    __syncthreads();
    int gid = blockIdx.x * 256 + tid;
    int o = gid & 63;
    float sc = saff[o], sh = saff[64 + o];
    float v = (sc >= 0.f) ? Mx[gid] : Mn[gid];
    Xout[gid] = lrelu(fmaf(v, sc, sh));
}

// ---------------------------------------------------------------- stage-3 fused edge+pool
__global__ __launch_bounds__(256) void zpool_kernel(const float* __restrict__ P,
                                                    const int* __restrict__ idx,
                                                    const float* __restrict__ gsIn,
                                                    const float* __restrict__ g,
                                                    const float* __restrict__ b,
                                                    float* __restrict__ Xout) {
    __shared__ float saff[128];
    int tid = threadIdx.x;
    compute_affine(gsIn, g, b, saff, tid);
    __syncthreads();
    int gid = blockIdx.x * 256 + tid;
    int n = gid >> 6, o = gid & 63;
    float An = P[n * 128 + o];
    float Bn = P[n * 128 + 64 + o];
    float base = Bn - An;
    float mxz = -INFINITY, mnz = INFINITY;
    for (int kk = 0; kk < KNN; ++kk) {
        int m = idx[n * KNN + kk];
        float z = P[m * 128 + o] + base;
        mxz = fmaxf(mxz, z); mnz = fminf(mnz, z);
    }
    float sc = saff[o], sh = saff[64 + o];
    float v = (sc >= 0.f) ? mxz : mnz;
    Xout[gid] = lrelu(fmaf(v, sc, sh));
}

// ---------------------------------------------------------------- fused final MLP: 8 points/block
__global__ __launch_bounds__(128) void mlp_kernel(const float* __restrict__ x1,
                                                  const float* __restrict__ x2,
                                                  const float* __restrict__ x3,
                                                  const float* __restrict__ W9at,
                                                  const float* __restrict__ b9a,
                                                  const float* __restrict__ W9bt,
                                                  const float* __restrict__ b9b,
                                                  float* __restrict__ out) {
    __shared__ float hs[8][128];
    int tid = threadIdx.x;
    int j = tid;
    int n0 = blockIdx.x * 8;
    float acc[8];
    float bj = b9a[j];
#pragma unroll
    for (int p = 0; p < 8; ++p) acc[p] = bj;
    for (int c = 0; c < 64; ++c) {
        float w = W9at[c * 128 + j];
#pragma unroll
        for (int p = 0; p < 8; ++p) acc[p] = fmaf(x1[(n0 + p) * 64 + c], w, acc[p]);
    }
    for (int c = 0; c < 64; ++c) {
        float w = W9at[(64 + c) * 128 + j];
#pragma unroll
        for (int p = 0; p < 8; ++p) acc[p] = fmaf(x2[(n0 + p) * 64 + c], w, acc[p]);
    }
    for (int c = 0; c < 64; ++c) {
        float w = W9at[(128 + c) * 128 + j];
#pragma unroll
        for (int p = 0; p < 8; ++p) acc[p] = fmaf(x3[(n0 + p) * 64 + c], w, acc[p]);
    }
#pragma unroll
    for (int p = 0; p < 8; ++p) hs[p][j] = fmaxf(acc[p], 0.f);
    __syncthreads();
    int p2 = tid >> 4, j2 = tid & 15;
    float a = b9b[j2];
    for (int c = 0; c < 128; ++c) a = fmaf(hs[p2][c], W9bt[c * 16 + j2], a);
    out[j2 * NPTS + n0 + p2] = a;
}

// ---------------------------------------------------------------- launch
extern "C" void kernel_launch(void* const* d_in, const int* in_sizes, int n_in,
                              void* d_out, int out_size, void* d_ws, size_t ws_size,
                              hipStream_t stream) {
    const float* x   = (const float*)d_in[0];
    const float* W1  = (const float*)d_in[2];
    const float* g1  = (const float*)d_in[3];
    const float* b1  = (const float*)d_in[4];
    const float* W2  = (const float*)d_in[5];
    const float* g2  = (const float*)d_in[6];
    const float* b2  = (const float*)d_in[7];
    const float* W3  = (const float*)d_in[8];
    const float* g3  = (const float*)d_in[9];
    const float* b3  = (const float*)d_in[10];
    const float* W4  = (const float*)d_in[11];
    const float* g4  = (const float*)d_in[12];
    const float* b4  = (const float*)d_in[13];
    const float* W5  = (const float*)d_in[14];
    const float* g5  = (const float*)d_in[15];
    const float* b5  = (const float*)d_in[16];
    const float* W9a = (const float*)d_in[17];
    const float* b9a = (const float*)d_in[18];
    const float* W9b = (const float*)d_in[19];
    const float* b9b = (const float*)d_in[20];
    float* out = (float*)d_out;

    char* ws = (char*)d_ws;
    int*    idx    = (int*)(ws + 0);                 // 655360
    float4* pk     = (float4*)(ws + 655360);         // 131072
    float*  P      = (float*)(ws + 786432);          // 4 MB
    float*  Mx     = (float*)(ws + 4980736);         // 2 MB
    float*  Mn     = (float*)(ws + 7077888);         // 2 MB
    float*  gsAll  = (float*)(ws + 9175040);         // 20480
    float*  x1b    = (float*)(ws + 9195520);         // 2 MB
    float*  x2b    = (float*)(ws + 11292672);        // 2 MB
    float*  x3b    = (float*)(ws + 13389824);        // 2 MB
    float*  Wt1    = (float*)(ws + 15486976);        // 34304
    float*  Wt3    = (float*)(ws + 15521280);        // 32768
    float*  Wt5    = (float*)(ws + 15554048);        // 32768
    float*  W9at   = (float*)(ws + 15586816);        // 98304
    float*  W9bt   = (float*)(ws + 15685120);        // 8192
    float*  champ  = (float*)(ws + 15693312);        // 16 MB
    float*  theta  = (float*)(ws + 32470528);        // 32768
    int*    scount = (int*)(ws + 32503296);          // 32768
    int2*   surv   = (int2*)(ws + 32536064);         // 12.6 MB
    (void)ws_size; (void)in_sizes; (void)n_in; (void)out_size;

    float* gs1 = gsAll;
    float* gs2 = gsAll + 1 * NREP * 128;
    float* gs3 = gsAll + 2 * NREP * 128;
    float* gs4 = gsAll + 3 * NREP * 128;
    float* gs5 = gsAll + 4 * NREP * 128;

    prep_kernel<<<286, 256, 0, stream>>>(x, W1, W3, W5, W9a, W9b, pk, Wt1, Wt3, Wt5, W9at, W9bt, gsAll, scount);
    knn_champ<<<(NPTS / 16) * NSLICE, 256, 0, stream>>>(pk, champ);
    knn_theta<<<NPTS / 4, 256, 0, stream>>>(champ, theta);
    knn_filter<<<(NPTS / 16) * NSLICE, 256, 0, stream>>>(pk, theta, scount, surv);
    knn_select<<<NPTS / 4, 256, 0, stream>>>(pk, scount, surv, idx);

    // stage 1
    proj_kernel<<<NPTS / 8, 256, 0, stream>>>(x, 1, NPTS, 67, Wt1, P);
    zsum_kernel<<<NPTS / 4, 256, 0, stream>>>(P, idx, gs1);
    conv_gemm_kernel<<<NPTS * KNN / 80, 256, 0, stream>>>(P, idx, gs1, g1, b1, W2, gs2, Mx, Mn);
    pool_kernel<<<NPTS * 64 / 256, 256, 0, stream>>>(Mx, Mn, gs2, g2, b2, x1b);

    // stage 2
    proj_kernel<<<NPTS / 8, 256, 0, stream>>>(x1b, 64, 1, 64, Wt3, P);
    zsum_kernel<<<NPTS / 4, 256, 0, stream>>>(P, idx, gs3);
    conv_gemm_kernel<<<NPTS * KNN / 80, 256, 0, stream>>>(P, idx, gs3, g3, b3, W4, gs4, Mx, Mn);
    pool_kernel<<<NPTS * 64 / 256, 256, 0, stream>>>(Mx, Mn, gs4, g4, b4, x2b);

    // stage 3
    proj_kernel<<<NPTS / 8, 256, 0, stream>>>(x2b, 64, 1, 64, Wt5, P);
    zsum_kernel<<<NPTS / 4, 256, 0, stream>>>(P, idx, gs5);
    zpool_kernel<<<NPTS * 64 / 256, 256, 0, stream>>>(P, idx, gs5, g5, b5, x3b);

    // final MLP
    mlp_kernel<<<NPTS / 8, 128, 0, stream>>>(x1b, x2b, x3b, W9at, b9a, W9bt, b9b, out);
}

// Round 9
// 279.321 us; speedup vs baseline: 4.9831x; 1.1541x over previous
//
#include <hip/hip_runtime.h>

#define NPTS 8192
#define KNN  20
#define NREP 64
#define NSLICE 8
#define SLICE 1024
#define CAP 192

__device__ __forceinline__ float pair_dist4(float qx, float qy, float qz, float xxn, float4 c) {
    float dot = fmaf(qz, c.z, fmaf(qy, c.y, qx * c.x));
    return fmaf(2.f, dot, -xxn) - c.w;
}
__device__ __forceinline__ float self_sq(float dx, float dy, float dz) {
    return fmaf(dz, dz, fmaf(dy, dy, dx * dx));
}
__device__ __forceinline__ float lrelu(float v) { return (v >= 0.f) ? v : 0.2f * v; }

__device__ __forceinline__ void compute_affine(const float* __restrict__ gs,
                                               const float* __restrict__ g,
                                               const float* __restrict__ b,
                                               float* saff, int tid) {
    if (tid < 64) {
        float s = 0.f, ss = 0.f;
        for (int r = 0; r < NREP; ++r) { s += gs[r * 128 + tid]; ss += gs[r * 128 + 64 + tid]; }
        const float invM = 1.f / (float)(NPTS * KNN);
        float mean = s * invM;
        float var = ss * invM - mean * mean;
        float sc = g[tid] * rsqrtf(var + 1e-5f);
        saff[tid] = sc;
        saff[64 + tid] = b[tid] - mean * sc;
    }
}

// ---------------------------------------------------------------- prep (zeroes gsAll + scount)
__global__ __launch_bounds__(256) void prep_kernel(const float* __restrict__ x,
                                                   const float* __restrict__ W1,
                                                   const float* __restrict__ W3,
                                                   const float* __restrict__ W5,
                                                   const float* __restrict__ W9a,
                                                   const float* __restrict__ W9b,
                                                   float4* __restrict__ pk,
                                                   float* __restrict__ Wt1,
                                                   float* __restrict__ Wt3,
                                                   float* __restrict__ Wt5,
                                                   float* __restrict__ W9at,
                                                   float* __restrict__ W9bt,
                                                   float* __restrict__ gsAll,
                                                   int* __restrict__ scount) {
    int gid = blockIdx.x * 256 + threadIdx.x;
    if (gid < NPTS) {
        float dx = x[64 * NPTS + gid], dy = x[65 * NPTS + gid], dz = x[66 * NPTS + gid];
        pk[gid] = make_float4(dx, dy, dz, self_sq(dx, dy, dz));
        return;
    }
    gid -= NPTS;
    if (gid < 67 * 128) {
        int c = gid >> 7, o = gid & 127;
        Wt1[gid] = (o < 64) ? W1[o * 134 + c] : W1[(o - 64) * 134 + 67 + c];
        return;
    }
    gid -= 67 * 128;
    if (gid < 64 * 128) {
        int c = gid >> 7, o = gid & 127;
        Wt3[gid] = (o < 64) ? W3[o * 128 + c] : W3[(o - 64) * 128 + 64 + c];
        return;
    }
    gid -= 64 * 128;
    if (gid < 64 * 128) {
        int c = gid >> 7, o = gid & 127;
        Wt5[gid] = (o < 64) ? W5[o * 128 + c] : W5[(o - 64) * 128 + 64 + c];
        return;
    }
    gid -= 64 * 128;
    if (gid < 192 * 128) {
        int c = gid >> 7, j = gid & 127;
        W9at[gid] = W9a[j * 192 + c];
        return;
    }
    gid -= 192 * 128;
    if (gid < 128 * 16) {
        int c = gid >> 4, j = gid & 15;
        W9bt[gid] = W9b[j * 128 + c];
        return;
    }
    gid -= 128 * 16;
    if (gid < 5 * NREP * 128) { gsAll[gid] = 0.f; return; }
    gid -= 5 * NREP * 128;
    if (gid < NPTS) scount[gid] = 0;
}

// ---------------------------------------------------------------- kNN K1: per-(q,lane,slice) champions
__global__ __launch_bounds__(256) void knn_champ(const float4* __restrict__ pk,
                                                 float* __restrict__ champ) {
    __shared__ float4 cpt[SLICE];
    int tid = threadIdx.x, wid = tid >> 6, lane = tid & 63;
    int qg = blockIdx.x >> 3;
    int s  = blockIdx.x & 7;
    for (int i = tid; i < SLICE; i += 256) cpt[i] = pk[s * SLICE + i];
    int qbase = qg * 16 + wid * 4;
    float qx[4], qy[4], qz[4], xxn[4], mv[4];
#pragma unroll
    for (int qi = 0; qi < 4; ++qi) {
        float4 qp = pk[qbase + qi];
        qx[qi] = qp.x; qy[qi] = qp.y; qz[qi] = qp.z; xxn[qi] = qp.w;
        mv[qi] = -INFINITY;
    }
    __syncthreads();
    for (int t = 0; t < SLICE / 64; ++t) {
        float4 c = cpt[t * 64 + lane];
#pragma unroll
        for (int qi = 0; qi < 4; ++qi)
            mv[qi] = fmaxf(mv[qi], pair_dist4(qx[qi], qy[qi], qz[qi], xxn[qi], c));
    }
#pragma unroll
    for (int qi = 0; qi < 4; ++qi)
        champ[(qbase + qi) * 512 + s * 64 + lane] = mv[qi];
}

// ---------------------------------------------------------------- kNN K2: theta
__global__ __launch_bounds__(256) void knn_theta(const float* __restrict__ champ,
                                                 float* __restrict__ theta) {
    int tid = threadIdx.x, wid = tid >> 6, lane = tid & 63;
    int q = blockIdx.x * 4 + wid;
    float ch[8];
#pragma unroll
    for (int r = 0; r < 8; ++r) ch[r] = champ[q * 512 + r * 64 + lane];
    float th = -INFINITY;
    for (int r = 0; r < KNN; ++r) {
        float lm = ch[0];
#pragma unroll
        for (int j = 1; j < 8; ++j) lm = fmaxf(lm, ch[j]);
        float v = lm;
#pragma unroll
        for (int m = 32; m >= 1; m >>= 1) v = fmaxf(v, __shfl_xor(v, m));
        th = v;
        unsigned long long bm = __ballot(lm == v);
        if (lane == __ffsll(bm) - 1) {
            bool done = false;
#pragma unroll
            for (int j = 0; j < 8; ++j)
                if (!done && ch[j] == v) { ch[j] = -INFINITY; done = true; }
        }
    }
    if (lane == 0) theta[q] = th - 1e-3f;
}

// ---------------------------------------------------------------- kNN K3: filter + compact survivors
__global__ __launch_bounds__(256) void knn_filter(const float4* __restrict__ pk,
                                                  const float* __restrict__ theta,
                                                  int* __restrict__ scount,
                                                  int2* __restrict__ surv) {
    __shared__ float4 cpt[SLICE];
    int tid = threadIdx.x, wid = tid >> 6, lane = tid & 63;
    int qg = blockIdx.x >> 3;
    int s  = blockIdx.x & 7;
    for (int i = tid; i < SLICE; i += 256) cpt[i] = pk[s * SLICE + i];
    int qbase = qg * 16 + wid * 4;
    float qx[4], qy[4], qz[4], xxn[4], th[4];
#pragma unroll
    for (int qi = 0; qi < 4; ++qi) {
        float4 qp = pk[qbase + qi];
        qx[qi] = qp.x; qy[qi] = qp.y; qz[qi] = qp.z; xxn[qi] = qp.w;
        th[qi] = theta[qbase + qi];
    }
    __syncthreads();
    for (int t = 0; t < SLICE / 64; ++t) {
        int gi = s * SLICE + t * 64 + lane;
        float4 c = cpt[t * 64 + lane];
#pragma unroll
        for (int qi = 0; qi < 4; ++qi) {
            float d = pair_dist4(qx[qi], qy[qi], qz[qi], xxn[qi], c);
            bool p = (d >= th[qi]);
            unsigned long long mk = __ballot(p);
            if (mk) {
                int q = qbase + qi;
                int src = __ffsll(mk) - 1;
                int base = 0;
                if (lane == src) base = atomicAdd(&scount[q], (int)__popcll(mk));
                base = __shfl(base, src);
                if (p) {
                    int pos = base + (int)__popcll(mk & ((1ull << lane) - 1));
                    if (pos < CAP) surv[q * CAP + pos] = make_int2(__float_as_int(d), gi);
                }
            }
        }
    }
}

// ---------------------------------------------------------------- kNN K4: select top-20 + fused zsum1
__global__ __launch_bounds__(256) void knn_select_zsum(const float4* __restrict__ pk,
                                                       const int* __restrict__ scount,
                                                       const int2* __restrict__ surv,
                                                       int* __restrict__ idx_out,
                                                       const float* __restrict__ P,
                                                       float* __restrict__ gs) {
    int tid = threadIdx.x, wid = tid >> 6, lane = tid & 63;
    int q = blockIdx.x * 4 + wid;
    int cnt = scount[q];
    int mi_keep = 0;
    if (cnt <= CAP) {
        float sv[3]; int si[3];
#pragma unroll
        for (int r = 0; r < 3; ++r) {
            int j = r * 64 + lane;
            bool ok = j < cnt;
            int2 pr = ok ? surv[q * CAP + j] : make_int2(0, 0);
            sv[r] = ok ? __int_as_float(pr.x) : -INFINITY;
            si[r] = ok ? pr.y : 0x7fffffff;
        }
        for (int r = 0; r < KNN; ++r) {
            float lv = -INFINITY; int li = 0x7fffffff; int ls = -1;
#pragma unroll
            for (int s3 = 0; s3 < 3; ++s3) {
                bool g = (sv[s3] > lv) || (sv[s3] == lv && si[s3] < li);
                if (g) { lv = sv[s3]; li = si[s3]; ls = s3; }
            }
            float wv = lv; int wi = li;
#pragma unroll
            for (int m = 32; m >= 1; m >>= 1) {
                float ov = __shfl_xor(wv, m); int oi = __shfl_xor(wi, m);
                if (ov > wv || (ov == wv && oi < wi)) { wv = ov; wi = oi; }
            }
            if (lv == wv && li == wi) {
#pragma unroll
                for (int s3 = 0; s3 < 3; ++s3)
                    if (s3 == ls) { sv[s3] = -INFINITY; si[s3] = 0x7fffffff; }
            }
            if (lane == 0) idx_out[q * KNN + r] = wi;
            if (lane == r) mi_keep = wi;
        }
    } else {
        // exact fallback: 20-round lex-max scan over all points
        float4 qp = pk[q];
        float qx = qp.x, qy = qp.y, qz = qp.z, xxn = qp.w;
        float pv = INFINITY; int pi = -1;
        for (int r = 0; r < KNN; ++r) {
            float bv = -INFINITY; int bi = 0x7fffffff;
            for (int t = 0; t < NPTS / 64; ++t) {
                int i = t * 64 + lane;
                float d = pair_dist4(qx, qy, qz, xxn, pk[i]);
                bool adm = (d < pv) || (d == pv && i > pi);
                if (adm && (d > bv || (d == bv && i < bi))) { bv = d; bi = i; }
            }
            float wv = bv; int wi = bi;
#pragma unroll
            for (int m = 32; m >= 1; m >>= 1) {
                float ov = __shfl_xor(wv, m); int oi = __shfl_xor(wi, m);
                if (ov > wv || (ov == wv && oi < wi)) { wv = ov; wi = oi; }
            }
            if (lane == 0) idx_out[q * KNN + r] = wi;
            if (lane == r) mi_keep = wi;
            pv = wv; pi = wi;
        }
    }
    // fused zsum for this query (o = lane)
    float An = P[q * 128 + lane];
    float Bn = P[q * 128 + 64 + lane];
    float base = Bn - An;
    float sum = 0.f, ss = 0.f;
    for (int kk = 0; kk < KNN; ++kk) {
        int m = __shfl(mi_keep, kk);
        float z = P[(size_t)m * 128 + lane] + base;
        sum += z;
        ss = fmaf(z, z, ss);
    }
    float* gg = gs + (blockIdx.x & (NREP - 1)) * 128;
    atomicAdd(gg + lane, sum);
    atomicAdd(gg + 64 + lane, ss);
}

// ---------------------------------------------------------------- projection (stage 1 only)
__global__ __launch_bounds__(256) void proj_kernel(const float* __restrict__ X,
                                                   int sn, int sc, int Cin,
                                                   const float* __restrict__ Wt,
                                                   float* __restrict__ P) {
    int tid = threadIdx.x;
    int o = tid & 127;
    int h = tid >> 7;
    int n0 = blockIdx.x * 8 + h * 4;
    float acc[4] = {0.f, 0.f, 0.f, 0.f};
    for (int c = 0; c < Cin; ++c) {
        float w = Wt[c * 128 + o];
#pragma unroll
        for (int i = 0; i < 4; ++i) acc[i] = fmaf(X[(n0 + i) * sn + c * sc], w, acc[i]);
    }
#pragma unroll
    for (int i = 0; i < 4; ++i) P[(n0 + i) * 128 + o] = acc[i];
}

// ---------------------------------------------------------------- z stats (stages 2,3)
__global__ __launch_bounds__(256) void zsum_kernel(const float* __restrict__ P,
                                                   const int* __restrict__ idx,
                                                   float* __restrict__ gs) {
    int tid = threadIdx.x;
    int o = tid & 63;
    float sum = 0.f, sumsq = 0.f;
    int n0 = blockIdx.x * 4;
    for (int ni = 0; ni < 4; ++ni) {
        int n = n0 + ni;
        float An = P[n * 128 + o];
        float Bn = P[n * 128 + 64 + o];
        float base = Bn - An;
        for (int kk = tid >> 6; kk < KNN; kk += 4) {
            int m = idx[n * KNN + kk];
            float z = P[m * 128 + o] + base;
            sum += z;
            sumsq = fmaf(z, z, sumsq);
        }
    }
    __shared__ float s1[256], s2[256];
    s1[tid] = sum; s2[tid] = sumsq;
    __syncthreads();
    if (tid < 64) {
        float a = s1[tid] + s1[tid + 64] + s1[tid + 128] + s1[tid + 192];
        float b = s2[tid] + s2[tid + 64] + s2[tid + 128] + s2[tid + 192];
        float* g = gs + (blockIdx.x & (NREP - 1)) * 128;
        atomicAdd(g + tid, a);
        atomicAdd(g + 64 + tid, b);
    }
}

// ---------------------------------------------------------------- conv GEMM: 80-row n-aligned tile
__global__ __launch_bounds__(256) void conv_gemm_kernel(const float* __restrict__ P,
                                                        const int* __restrict__ idx,
                                                        const float* __restrict__ gsIn,
                                                        const float* __restrict__ gIn,
                                                        const float* __restrict__ bIn,
                                                        const float* __restrict__ W,
                                                        float* __restrict__ gsOut,
                                                        float* __restrict__ Mx,
                                                        float* __restrict__ Mn) {
    __shared__ float As[80][68];
    __shared__ float Ws[64][68];
    __shared__ float saff[128];
    int tid = threadIdx.x;
    int r0 = blockIdx.x * 80;

    compute_affine(gsIn, gIn, bIn, saff, tid);
    for (int i2 = tid; i2 < 1024; i2 += 256) {
        int rr = i2 >> 4, c4 = (i2 & 15) * 4;
        *(float4*)&Ws[rr][c4] = *(const float4*)&W[rr * 64 + c4];
    }
    __syncthreads();

    for (int i2 = tid; i2 < 1280; i2 += 256) {
        int rr = i2 >> 4, c4 = (i2 & 15) * 4;
        int grow = r0 + rr;
        int n = grow / 20;
        int m = idx[grow];
        float4 zn = *(const float4*)&P[(size_t)m * 128 + c4];
        float4 an = *(const float4*)&P[(size_t)n * 128 + c4];
        float4 bn = *(const float4*)&P[(size_t)n * 128 + 64 + c4];
        float4 ov; float z;
        z = zn.x + (bn.x - an.x); ov.x = lrelu(fmaf(z, saff[c4 + 0], saff[64 + c4 + 0]));
        z = zn.y + (bn.y - an.y); ov.y = lrelu(fmaf(z, saff[c4 + 1], saff[64 + c4 + 1]));
        z = zn.z + (bn.z - an.z); ov.z = lrelu(fmaf(z, saff[c4 + 2], saff[64 + c4 + 2]));
        z = zn.w + (bn.w - an.w); ov.w = lrelu(fmaf(z, saff[c4 + 3], saff[64 + c4 + 3]));
        *(float4*)&As[rr][c4] = ov;
    }
    __syncthreads();

    int ty = tid >> 4, tx = tid & 15;
    float acc[5][4];
#pragma unroll
    for (int i = 0; i < 5; ++i)
#pragma unroll
        for (int j = 0; j < 4; ++j) acc[i][j] = 0.f;

    for (int c4 = 0; c4 < 64; c4 += 4) {
        float4 a4[5], w4[4];
#pragma unroll
        for (int i = 0; i < 5; ++i) a4[i] = *(const float4*)&As[ty + 16 * i][c4];
#pragma unroll
        for (int j = 0; j < 4; ++j) w4[j] = *(const float4*)&Ws[tx + 16 * j][c4];
#pragma unroll
        for (int i = 0; i < 5; ++i)
#pragma unroll
            for (int j = 0; j < 4; ++j) {
                acc[i][j] = fmaf(a4[i].x, w4[j].x, acc[i][j]);
                acc[i][j] = fmaf(a4[i].y, w4[j].y, acc[i][j]);
                acc[i][j] = fmaf(a4[i].z, w4[j].z, acc[i][j]);
                acc[i][j] = fmaf(a4[i].w, w4[j].w, acc[i][j]);
            }
    }
    __syncthreads();

#pragma unroll
    for (int i = 0; i < 5; ++i)
#pragma unroll
        for (int j = 0; j < 4; ++j) As[ty + 16 * i][tx + 16 * j] = acc[i][j];
    __syncthreads();

    int a = tid >> 6, o = tid & 63;
    float mxv = -INFINITY, mnv = INFINITY, s = 0.f, ss = 0.f;
#pragma unroll
    for (int r = 0; r < 20; ++r) {
        float v = As[20 * a + r][o];
        mxv = fmaxf(mxv, v); mnv = fminf(mnv, v);
        s += v; ss = fmaf(v, v, ss);
    }
    int n = blockIdx.x * 4 + a;
    Mx[n * 64 + o] = mxv;
    Mn[n * 64 + o] = mnv;
    float* sred = &Ws[0][0];
    float* ssred = sred + 256;
    sred[a * 64 + o] = s;
    ssred[a * 64 + o] = ss;
    __syncthreads();
    if (tid < 64) {
        float ts = sred[tid] + sred[64 + tid] + sred[128 + tid] + sred[192 + tid];
        float tss = ssred[tid] + ssred[64 + tid] + ssred[128 + tid] + ssred[192 + tid];
        float* gg = gsOut + (blockIdx.x & (NREP - 1)) * 128;
        atomicAdd(gg + tid, ts);
        atomicAdd(gg + 64 + tid, tss);
    }
}

// ---------------------------------------------------------------- pool + next-stage projection
__global__ __launch_bounds__(256) void pool_proj_kernel(const float* __restrict__ Mx,
                                                        const float* __restrict__ Mn,
                                                        const float* __restrict__ gsIn,
                                                        const float* __restrict__ g,
                                                        const float* __restrict__ b,
                                                        const float* __restrict__ Wt,
                                                        float* __restrict__ Xout,
                                                        float* __restrict__ Pout) {
    __shared__ float saff[128];
    __shared__ float xs[4][64];
    int tid = threadIdx.x;
    compute_affine(gsIn, g, b, saff, tid);
    __syncthreads();
    int n0 = blockIdx.x * 4;
    int pp = tid >> 6, o = tid & 63;
    float sc = saff[o], sh = saff[64 + o];
    float v = (sc >= 0.f) ? Mx[(n0 + pp) * 64 + o] : Mn[(n0 + pp) * 64 + o];
    float xv = lrelu(fmaf(v, sc, sh));
    Xout[(n0 + pp) * 64 + o] = xv;
    xs[pp][o] = xv;
    __syncthreads();
    int o2 = tid & 127, h = tid >> 7;
    int p0 = h * 2, p1 = h * 2 + 1;
    float a0 = 0.f, a1 = 0.f;
    for (int c = 0; c < 64; ++c) {
        float w = Wt[c * 128 + o2];
        a0 = fmaf(xs[p0][c], w, a0);
        a1 = fmaf(xs[p1][c], w, a1);
    }
    Pout[(n0 + p0) * 128 + o2] = a0;
    Pout[(n0 + p1) * 128 + o2] = a1;
}

// ---------------------------------------------------------------- stage-3 fused edge+pool
__global__ __launch_bounds__(256) void zpool_kernel(const float* __restrict__ P,
                                                    const int* __restrict__ idx,
                                                    const float* __restrict__ gsIn,
                                                    const float* __restrict__ g,
                                                    const float* __restrict__ b,
                                                    float* __restrict__ Xout) {
    __shared__ float saff[128];
    int tid = threadIdx.x;
    compute_affine(gsIn, g, b, saff, tid);
    __syncthreads();
    int gid = blockIdx.x * 256 + tid;
    int n = gid >> 6, o = gid & 63;
    float An = P[n * 128 + o];
    float Bn = P[n * 128 + 64 + o];
    float base = Bn - An;
    float mxz = -INFINITY, mnz = INFINITY;
    for (int kk = 0; kk < KNN; ++kk) {
        int m = idx[n * KNN + kk];
        float z = P[m * 128 + o] + base;
        mxz = fmaxf(mxz, z); mnz = fminf(mnz, z);
    }
    float sc = saff[o], sh = saff[64 + o];
    float v = (sc >= 0.f) ? mxz : mnz;
    Xout[gid] = lrelu(fmaf(v, sc, sh));
}

// ---------------------------------------------------------------- fused final MLP
__global__ __launch_bounds__(128) void mlp_kernel(const float* __restrict__ x1,
                                                  const float* __restrict__ x2,
                                                  const float* __restrict__ x3,
                                                  const float* __restrict__ W9at,
                                                  const float* __restrict__ b9a,
                                                  const float* __restrict__ W9bt,
                                                  const float* __restrict__ b9b,
                                                  float* __restrict__ out) {
    __shared__ float hs[8][128];
    int tid = threadIdx.x;
    int j = tid;
    int n0 = blockIdx.x * 8;
    float acc[8];
    float bj = b9a[j];
#pragma unroll
    for (int p = 0; p < 8; ++p) acc[p] = bj;
    for (int c = 0; c < 64; ++c) {
        float w = W9at[c * 128 + j];
#pragma unroll
        for (int p = 0; p < 8; ++p) acc[p] = fmaf(x1[(n0 + p) * 64 + c], w, acc[p]);
    }
    for (int c = 0; c < 64; ++c) {
        float w = W9at[(64 + c) * 128 + j];
#pragma unroll
        for (int p = 0; p < 8; ++p) acc[p] = fmaf(x2[(n0 + p) * 64 + c], w, acc[p]);
    }
    for (int c = 0; c < 64; ++c) {
        float w = W9at[(128 + c) * 128 + j];
#pragma unroll
        for (int p = 0; p < 8; ++p) acc[p] = fmaf(x3[(n0 + p) * 64 + c], w, acc[p]);
    }
#pragma unroll
    for (int p = 0; p < 8; ++p) hs[p][j] = fmaxf(acc[p], 0.f);
    __syncthreads();
    int p2 = tid >> 4, j2 = tid & 15;
    float a = b9b[j2];
    for (int c = 0; c < 128; ++c) a = fmaf(hs[p2][c], W9bt[c * 16 + j2], a);
    out[j2 * NPTS + n0 + p2] = a;
}

// ---------------------------------------------------------------- launch
extern "C" void kernel_launch(void* const* d_in, const int* in_sizes, int n_in,
                              void* d_out, int out_size, void* d_ws, size_t ws_size,
                              hipStream_t stream) {
    const float* x   = (const float*)d_in[0];
    const float* W1  = (const float*)d_in[2];
    const float* g1  = (const float*)d_in[3];
    const float* b1  = (const float*)d_in[4];
    const float* W2  = (const float*)d_in[5];
    const float* g2  = (const float*)d_in[6];
    const float* b2  = (const float*)d_in[7];
    const float* W3  = (const float*)d_in[8];
    const float* g3  = (const float*)d_in[9];
    const float* b3  = (const float*)d_in[10];
    const float* W4  = (const float*)d_in[11];
    const float* g4  = (const float*)d_in[12];
    const float* b4  = (const float*)d_in[13];
    const float* W5  = (const float*)d_in[14];
    const float* g5  = (const float*)d_in[15];
    const float* b5  = (const float*)d_in[16];
    const float* W9a = (const float*)d_in[17];
    const float* b9a = (const float*)d_in[18];
    const float* W9b = (const float*)d_in[19];
    const float* b9b = (const float*)d_in[20];
    float* out = (float*)d_out;

    char* ws = (char*)d_ws;
    int*    idx    = (int*)(ws + 0);                 // 655360
    float4* pk     = (float4*)(ws + 655360);         // 131072
    float*  P      = (float*)(ws + 786432);          // 4 MB
    float*  Mx     = (float*)(ws + 4980736);         // 2 MB
    float*  Mn     = (float*)(ws + 7077888);         // 2 MB
    float*  gsAll  = (float*)(ws + 9175040);         // 163840
    float*  x1b    = (float*)(ws + 9338880);         // 2 MB
    float*  x2b    = (float*)(ws + 11436032);        // 2 MB
    float*  x3b    = (float*)(ws + 13533184);        // 2 MB
    float*  Wt1    = (float*)(ws + 15630336);        // 34304
    float*  Wt3    = (float*)(ws + 15664640);        // 32768
    float*  Wt5    = (float*)(ws + 15697408);        // 32768
    float*  W9at   = (float*)(ws + 15730176);        // 98304
    float*  W9bt   = (float*)(ws + 15828480);        // 8192
    float*  champ  = (float*)(ws + 15836672);        // 16 MB
    float*  theta  = (float*)(ws + 32613888);        // 32768
    int*    scount = (int*)(ws + 32646656);          // 32768
    int2*   surv   = (int2*)(ws + 32679424);         // 12.6 MB
    (void)ws_size; (void)in_sizes; (void)n_in; (void)out_size;

    float* gs1 = gsAll;
    float* gs2 = gsAll + 1 * NREP * 128;
    float* gs3 = gsAll + 2 * NREP * 128;
    float* gs4 = gsAll + 3 * NREP * 128;
    float* gs5 = gsAll + 4 * NREP * 128;

    prep_kernel<<<426, 256, 0, stream>>>(x, W1, W3, W5, W9a, W9b, pk, Wt1, Wt3, Wt5, W9at, W9bt, gsAll, scount);
    proj_kernel<<<NPTS / 8, 256, 0, stream>>>(x, 1, NPTS, 67, Wt1, P);
    knn_champ<<<(NPTS / 16) * NSLICE, 256, 0, stream>>>(pk, champ);
    knn_theta<<<NPTS / 4, 256, 0, stream>>>(champ, theta);
    knn_filter<<<(NPTS / 16) * NSLICE, 256, 0, stream>>>(pk, theta, scount, surv);
    knn_select_zsum<<<NPTS / 4, 256, 0, stream>>>(pk, scount, surv, idx, P, gs1);

    // stage 1
    conv_gemm_kernel<<<NPTS * KNN / 80, 256, 0, stream>>>(P, idx, gs1, g1, b1, W2, gs2, Mx, Mn);
    pool_proj_kernel<<<NPTS / 4, 256, 0, stream>>>(Mx, Mn, gs2, g2, b2, Wt3, x1b, P);

    // stage 2
    zsum_kernel<<<NPTS / 4, 256, 0, stream>>>(P, idx, gs3);
    conv_gemm_kernel<<<NPTS * KNN / 80, 256, 0, stream>>>(P, idx, gs3, g3, b3, W4, gs4, Mx, Mn);
    pool_proj_kernel<<<NPTS / 4, 256, 0, stream>>>(Mx, Mn, gs4, g4, b4, Wt5, x2b, P);

    // stage 3
    zsum_kernel<<<NPTS / 4, 256, 0, stream>>>(P, idx, gs5);
    zpool_kernel<<<NPTS * 64 / 256, 256, 0, stream>>>(P, idx, gs5, g5, b5, x3b);

    // final MLP
    mlp_kernel<<<NPTS / 8, 128, 0, stream>>>(x1b, x2b, x3b, W9at, b9a, W9bt, b9b, out);
}

// Round 10
// 260.238 us; speedup vs baseline: 5.3485x; 1.0733x over previous
//
#include <hip/hip_runtime.h>

#define NPTS 8192
#define KNN  20
#define NREP 64
#define NSLICE 8
#define SLICE 1024
#define CAP 256
#define THSUB 2048

__device__ __forceinline__ float pair_dist4(float qx, float qy, float qz, float xxn, float4 c) {
    float dot = fmaf(qz, c.z, fmaf(qy, c.y, qx * c.x));
    return fmaf(2.f, dot, -xxn) - c.w;
}
__device__ __forceinline__ float self_sq(float dx, float dy, float dz) {
    return fmaf(dz, dz, fmaf(dy, dy, dx * dx));
}
__device__ __forceinline__ float lrelu(float v) { return (v >= 0.f) ? v : 0.2f * v; }

__device__ __forceinline__ void compute_affine(const float* __restrict__ gs,
                                               const float* __restrict__ g,
                                               const float* __restrict__ b,
                                               float* saff, int tid) {
    if (tid < 64) {
        float s = 0.f, ss = 0.f;
        for (int r = 0; r < NREP; ++r) { s += gs[r * 128 + tid]; ss += gs[r * 128 + 64 + tid]; }
        const float invM = 1.f / (float)(NPTS * KNN);
        float mean = s * invM;
        float var = ss * invM - mean * mean;
        float sc = g[tid] * rsqrtf(var + 1e-5f);
        saff[tid] = sc;
        saff[64 + tid] = b[tid] - mean * sc;
    }
}

// ---------------------------------------------------------------- prep (zeroes gsAll + scount)
__global__ __launch_bounds__(256) void prep_kernel(const float* __restrict__ x,
                                                   const float* __restrict__ W1,
                                                   const float* __restrict__ W3,
                                                   const float* __restrict__ W5,
                                                   const float* __restrict__ W9a,
                                                   const float* __restrict__ W9b,
                                                   float4* __restrict__ pk,
                                                   float* __restrict__ Wt1,
                                                   float* __restrict__ Wt3,
                                                   float* __restrict__ Wt5,
                                                   float* __restrict__ W9at,
                                                   float* __restrict__ W9bt,
                                                   float* __restrict__ gsAll,
                                                   int* __restrict__ scount) {
    int gid = blockIdx.x * 256 + threadIdx.x;
    if (gid < NPTS) {
        float dx = x[64 * NPTS + gid], dy = x[65 * NPTS + gid], dz = x[66 * NPTS + gid];
        pk[gid] = make_float4(dx, dy, dz, self_sq(dx, dy, dz));
        return;
    }
    gid -= NPTS;
    if (gid < 67 * 128) {
        int c = gid >> 7, o = gid & 127;
        Wt1[gid] = (o < 64) ? W1[o * 134 + c] : W1[(o - 64) * 134 + 67 + c];
        return;
    }
    gid -= 67 * 128;
    if (gid < 64 * 128) {
        int c = gid >> 7, o = gid & 127;
        Wt3[gid] = (o < 64) ? W3[o * 128 + c] : W3[(o - 64) * 128 + 64 + c];
        return;
    }
    gid -= 64 * 128;
    if (gid < 64 * 128) {
        int c = gid >> 7, o = gid & 127;
        Wt5[gid] = (o < 64) ? W5[o * 128 + c] : W5[(o - 64) * 128 + 64 + c];
        return;
    }
    gid -= 64 * 128;
    if (gid < 192 * 128) {
        int c = gid >> 7, j = gid & 127;
        W9at[gid] = W9a[j * 192 + c];
        return;
    }
    gid -= 192 * 128;
    if (gid < 128 * 16) {
        int c = gid >> 4, j = gid & 15;
        W9bt[gid] = W9b[j * 128 + c];
        return;
    }
    gid -= 128 * 16;
    if (gid < 5 * NREP * 128) { gsAll[gid] = 0.f; return; }
    gid -= 5 * NREP * 128;
    if (gid < NPTS) scount[gid] = 0;
}

// ---------------------------------------------------------------- kNN theta (2048-subset) + stage-1 proj
// blocks [0,512): theta for 16 queries each; blocks [512,1536): proj1 for 8 points each.
__global__ __launch_bounds__(256) void knn_theta_proj(const float4* __restrict__ pk,
                                                      float* __restrict__ theta,
                                                      const float* __restrict__ X,
                                                      const float* __restrict__ Wt1,
                                                      float* __restrict__ P) {
    __shared__ float4 cpt[THSUB];
    int tid = threadIdx.x;
    if (blockIdx.x >= 512) {
        int bb = blockIdx.x - 512;
        int o = tid & 127, h = tid >> 7;
        int n0 = bb * 8 + h * 4;
        float acc[4] = {0.f, 0.f, 0.f, 0.f};
        for (int c = 0; c < 67; ++c) {
            float w = Wt1[c * 128 + o];
#pragma unroll
            for (int i = 0; i < 4; ++i) acc[i] = fmaf(X[(n0 + i) + c * NPTS], w, acc[i]);
        }
#pragma unroll
        for (int i = 0; i < 4; ++i) P[(n0 + i) * 128 + o] = acc[i];
        return;
    }
    int wid = tid >> 6, lane = tid & 63;
    int qbase = blockIdx.x * 16 + wid * 4;
    for (int i = tid; i < THSUB; i += 256) cpt[i] = pk[i];
    float qx[4], qy[4], qz[4], xxn[4], mv[4];
#pragma unroll
    for (int qi = 0; qi < 4; ++qi) {
        float4 qp = pk[qbase + qi];
        qx[qi] = qp.x; qy[qi] = qp.y; qz[qi] = qp.z; xxn[qi] = qp.w;
        mv[qi] = -INFINITY;
    }
    __syncthreads();
    for (int t = 0; t < THSUB / 64; ++t) {
        float4 c = cpt[t * 64 + lane];
#pragma unroll
        for (int qi = 0; qi < 4; ++qi)
            mv[qi] = fmaxf(mv[qi], pair_dist4(qx[qi], qy[qi], qz[qi], xxn[qi], c));
    }
    // theta = 20th largest of the 64 lane maxima (lane sets disjoint => >=20 distinct points
    // in the 2048-subset => theta <= v20 of subset <= v20 of full set)
#pragma unroll 1
    for (int qi = 0; qi < 4; ++qi) {
        float sel = mv[qi];
        float th = -INFINITY;
        for (int r = 0; r < KNN; ++r) {
            float v = sel;
#pragma unroll
            for (int m = 32; m >= 1; m >>= 1) v = fmaxf(v, __shfl_xor(v, m));
            th = v;
            unsigned long long bm = __ballot(sel == v);
            if (lane == __ffsll(bm) - 1) sel = -INFINITY;
        }
        if (lane == 0) theta[qbase + qi] = th - 1e-3f;
    }
}

// ---------------------------------------------------------------- kNN filter: compact survivors
__global__ __launch_bounds__(256) void knn_filter(const float4* __restrict__ pk,
                                                  const float* __restrict__ theta,
                                                  int* __restrict__ scount,
                                                  int2* __restrict__ surv) {
    __shared__ float4 cpt[SLICE];
    int tid = threadIdx.x, wid = tid >> 6, lane = tid & 63;
    int qg = blockIdx.x >> 3;
    int s  = blockIdx.x & 7;
    for (int i = tid; i < SLICE; i += 256) cpt[i] = pk[s * SLICE + i];
    int qbase = qg * 16 + wid * 4;
    float qx[4], qy[4], qz[4], xxn[4], th[4];
#pragma unroll
    for (int qi = 0; qi < 4; ++qi) {
        float4 qp = pk[qbase + qi];
        qx[qi] = qp.x; qy[qi] = qp.y; qz[qi] = qp.z; xxn[qi] = qp.w;
        th[qi] = theta[qbase + qi];
    }
    __syncthreads();
    for (int t = 0; t < SLICE / 64; ++t) {
        int gi = s * SLICE + t * 64 + lane;
        float4 c = cpt[t * 64 + lane];
#pragma unroll
        for (int qi = 0; qi < 4; ++qi) {
            float d = pair_dist4(qx[qi], qy[qi], qz[qi], xxn[qi], c);
            bool p = (d >= th[qi]);
            unsigned long long mk = __ballot(p);
            if (mk) {
                int q = qbase + qi;
                int src = __ffsll(mk) - 1;
                int base = 0;
                if (lane == src) base = atomicAdd(&scount[q], (int)__popcll(mk));
                base = __shfl(base, src);
                if (p) {
                    int pos = base + (int)__popcll(mk & ((1ull << lane) - 1));
                    if (pos < CAP) surv[q * CAP + pos] = make_int2(__float_as_int(d), gi);
                }
            }
        }
    }
}

// ---------------------------------------------------------------- kNN select top-20 + fused zsum1
__global__ __launch_bounds__(256) void knn_select_zsum(const float4* __restrict__ pk,
                                                       const int* __restrict__ scount,
                                                       const int2* __restrict__ surv,
                                                       int* __restrict__ idx_out,
                                                       const float* __restrict__ P,
                                                       float* __restrict__ gs) {
    int tid = threadIdx.x, wid = tid >> 6, lane = tid & 63;
    int q = blockIdx.x * 4 + wid;
    int cnt = scount[q];
    int mi_keep = 0;
    if (cnt <= CAP) {
        float sv[4]; int si[4];
#pragma unroll
        for (int r = 0; r < 4; ++r) {
            int j = r * 64 + lane;
            bool ok = j < cnt;
            int2 pr = ok ? surv[q * CAP + j] : make_int2(0, 0);
            sv[r] = ok ? __int_as_float(pr.x) : -INFINITY;
            si[r] = ok ? pr.y : 0x7fffffff;
        }
        for (int r = 0; r < KNN; ++r) {
            float lv = -INFINITY; int li = 0x7fffffff; int ls = -1;
#pragma unroll
            for (int s3 = 0; s3 < 4; ++s3) {
                bool g = (sv[s3] > lv) || (sv[s3] == lv && si[s3] < li);
                if (g) { lv = sv[s3]; li = si[s3]; ls = s3; }
            }
            float wv = lv; int wi = li;
#pragma unroll
            for (int m = 32; m >= 1; m >>= 1) {
                float ov = __shfl_xor(wv, m); int oi = __shfl_xor(wi, m);
                if (ov > wv || (ov == wv && oi < wi)) { wv = ov; wi = oi; }
            }
            if (lv == wv && li == wi) {
#pragma unroll
                for (int s3 = 0; s3 < 4; ++s3)
                    if (s3 == ls) { sv[s3] = -INFINITY; si[s3] = 0x7fffffff; }
            }
            if (lane == 0) idx_out[q * KNN + r] = wi;
            if (lane == r) mi_keep = wi;
        }
    } else {
        // exact fallback: 20-round lex-max scan over all points
        float4 qp = pk[q];
        float qx = qp.x, qy = qp.y, qz = qp.z, xxn = qp.w;
        float pv = INFINITY; int pi = -1;
        for (int r = 0; r < KNN; ++r) {
            float bv = -INFINITY; int bi = 0x7fffffff;
            for (int t = 0; t < NPTS / 64; ++t) {
                int i = t * 64 + lane;
                float d = pair_dist4(qx, qy, qz, xxn, pk[i]);
                bool adm = (d < pv) || (d == pv && i > pi);
                if (adm && (d > bv || (d == bv && i < bi))) { bv = d; bi = i; }
            }
            float wv = bv; int wi = bi;
#pragma unroll
            for (int m = 32; m >= 1; m >>= 1) {
                float ov = __shfl_xor(wv, m); int oi = __shfl_xor(wi, m);
                if (ov > wv || (ov == wv && oi < wi)) { wv = ov; wi = oi; }
            }
            if (lane == 0) idx_out[q * KNN + r] = wi;
            if (lane == r) mi_keep = wi;
            pv = wv; pi = wi;
        }
    }
    // fused zsum for this query (o = lane)
    float An = P[q * 128 + lane];
    float Bn = P[q * 128 + 64 + lane];
    float base = Bn - An;
    float sum = 0.f, ss = 0.f;
#pragma unroll
    for (int kk = 0; kk < KNN; ++kk) {
        int m = __shfl(mi_keep, kk);
        float z = P[(size_t)m * 128 + lane] + base;
        sum += z;
        ss = fmaf(z, z, ss);
    }
    float* gg = gs + (blockIdx.x & (NREP - 1)) * 128;
    atomicAdd(gg + lane, sum);
    atomicAdd(gg + 64 + lane, ss);
}

// ---------------------------------------------------------------- z stats (stages 2,3)
__global__ __launch_bounds__(256) void zsum_kernel(const float* __restrict__ P,
                                                   const int* __restrict__ idx,
                                                   float* __restrict__ gs) {
    int tid = threadIdx.x;
    int o = tid & 63;
    float sum = 0.f, sumsq = 0.f;
    int n0 = blockIdx.x * 4;
#pragma unroll
    for (int ni = 0; ni < 4; ++ni) {
        int n = n0 + ni;
        float An = P[n * 128 + o];
        float Bn = P[n * 128 + 64 + o];
        float base = Bn - An;
#pragma unroll
        for (int kk2 = 0; kk2 < 5; ++kk2) {
            int kk = (tid >> 6) + kk2 * 4;
            int m = idx[n * KNN + kk];
            float z = P[m * 128 + o] + base;
            sum += z;
            sumsq = fmaf(z, z, sumsq);
        }
    }
    __shared__ float s1[256], s2[256];
    s1[tid] = sum; s2[tid] = sumsq;
    __syncthreads();
    if (tid < 64) {
        float a = s1[tid] + s1[tid + 64] + s1[tid + 128] + s1[tid + 192];
        float b = s2[tid] + s2[tid + 64] + s2[tid + 128] + s2[tid + 192];
        float* g = gs + (blockIdx.x & (NREP - 1)) * 128;
        atomicAdd(g + tid, a);
        atomicAdd(g + 64 + tid, b);
    }
}

// ---------------------------------------------------------------- conv GEMM: 80-row n-aligned tile
__global__ __launch_bounds__(256) void conv_gemm_kernel(const float* __restrict__ P,
                                                        const int* __restrict__ idx,
                                                        const float* __restrict__ gsIn,
                                                        const float* __restrict__ gIn,
                                                        const float* __restrict__ bIn,
                                                        const float* __restrict__ W,
                                                        float* __restrict__ gsOut,
                                                        float* __restrict__ Mx,
                                                        float* __restrict__ Mn) {
    __shared__ float As[80][68];
    __shared__ float Ws[64][68];
    __shared__ float saff[128];
    int tid = threadIdx.x;
    int r0 = blockIdx.x * 80;

    compute_affine(gsIn, gIn, bIn, saff, tid);
    for (int i2 = tid; i2 < 1024; i2 += 256) {
        int rr = i2 >> 4, c4 = (i2 & 15) * 4;
        *(float4*)&Ws[rr][c4] = *(const float4*)&W[rr * 64 + c4];
    }
    __syncthreads();

#pragma unroll 5
    for (int i2 = tid; i2 < 1280; i2 += 256) {
        int rr = i2 >> 4, c4 = (i2 & 15) * 4;
        int grow = r0 + rr;
        int n = grow / 20;
        int m = idx[grow];
        float4 zn = *(const float4*)&P[(size_t)m * 128 + c4];
        float4 an = *(const float4*)&P[(size_t)n * 128 + c4];
        float4 bn = *(const float4*)&P[(size_t)n * 128 + 64 + c4];
        float4 ov; float z;
        z = zn.x + (bn.x - an.x); ov.x = lrelu(fmaf(z, saff[c4 + 0], saff[64 + c4 + 0]));
        z = zn.y + (bn.y - an.y); ov.y = lrelu(fmaf(z, saff[c4 + 1], saff[64 + c4 + 1]));
        z = zn.z + (bn.z - an.z); ov.z = lrelu(fmaf(z, saff[c4 + 2], saff[64 + c4 + 2]));
        z = zn.w + (bn.w - an.w); ov.w = lrelu(fmaf(z, saff[c4 + 3], saff[64 + c4 + 3]));
        *(float4*)&As[rr][c4] = ov;
    }
    __syncthreads();

    int ty = tid >> 4, tx = tid & 15;
    float acc[5][4];
#pragma unroll
    for (int i = 0; i < 5; ++i)
#pragma unroll
        for (int j = 0; j < 4; ++j) acc[i][j] = 0.f;

    for (int c4 = 0; c4 < 64; c4 += 4) {
        float4 a4[5], w4[4];
#pragma unroll
        for (int i = 0; i < 5; ++i) a4[i] = *(const float4*)&As[ty + 16 * i][c4];
#pragma unroll
        for (int j = 0; j < 4; ++j) w4[j] = *(const float4*)&Ws[tx + 16 * j][c4];
#pragma unroll
        for (int i = 0; i < 5; ++i)
#pragma unroll
            for (int j = 0; j < 4; ++j) {
                acc[i][j] = fmaf(a4[i].x, w4[j].x, acc[i][j]);
                acc[i][j] = fmaf(a4[i].y, w4[j].y, acc[i][j]);
                acc[i][j] = fmaf(a4[i].z, w4[j].z, acc[i][j]);
                acc[i][j] = fmaf(a4[i].w, w4[j].w, acc[i][j]);
            }
    }
    __syncthreads();

#pragma unroll
    for (int i = 0; i < 5; ++i)
#pragma unroll
        for (int j = 0; j < 4; ++j) As[ty + 16 * i][tx + 16 * j] = acc[i][j];
    __syncthreads();

    int a = tid >> 6, o = tid & 63;
    float mxv = -INFINITY, mnv = INFINITY, s = 0.f, ss = 0.f;
#pragma unroll
    for (int r = 0; r < 20; ++r) {
        float v = As[20 * a + r][o];
        mxv = fmaxf(mxv, v); mnv = fminf(mnv, v);
        s += v; ss = fmaf(v, v, ss);
    }
    int n = blockIdx.x * 4 + a;
    Mx[n * 64 + o] = mxv;
    Mn[n * 64 + o] = mnv;
    float* sred = &Ws[0][0];
    float* ssred = sred + 256;
    sred[a * 64 + o] = s;
    ssred[a * 64 + o] = ss;
    __syncthreads();
    if (tid < 64) {
        float ts = sred[tid] + sred[64 + tid] + sred[128 + tid] + sred[192 + tid];
        float tss = ssred[tid] + ssred[64 + tid] + ssred[128 + tid] + ssred[192 + tid];
        float* gg = gsOut + (blockIdx.x & (NREP - 1)) * 128;
        atomicAdd(gg + tid, ts);
        atomicAdd(gg + 64 + tid, tss);
    }
}

// ---------------------------------------------------------------- pool + next-stage projection
__global__ __launch_bounds__(256) void pool_proj_kernel(const float* __restrict__ Mx,
                                                        const float* __restrict__ Mn,
                                                        const float* __restrict__ gsIn,
                                                        const float* __restrict__ g,
                                                        const float* __restrict__ b,
                                                        const float* __restrict__ Wt,
                                                        float* __restrict__ Xout,
                                                        float* __restrict__ Pout) {
    __shared__ float saff[128];
    __shared__ float xs[4][64];
    int tid = threadIdx.x;
    compute_affine(gsIn, g, b, saff, tid);
    __syncthreads();
    int n0 = blockIdx.x * 4;
    int pp = tid >> 6, o = tid & 63;
    float sc = saff[o], sh = saff[64 + o];
    float v = (sc >= 0.f) ? Mx[(n0 + pp) * 64 + o] : Mn[(n0 + pp) * 64 + o];
    float xv = lrelu(fmaf(v, sc, sh));
    Xout[(n0 + pp) * 64 + o] = xv;
    xs[pp][o] = xv;
    __syncthreads();
    int o2 = tid & 127, h = tid >> 7;
    int p0 = h * 2, p1 = h * 2 + 1;
    float a0 = 0.f, a1 = 0.f;
    for (int c = 0; c < 64; ++c) {
        float w = Wt[c * 128 + o2];
        a0 = fmaf(xs[p0][c], w, a0);
        a1 = fmaf(xs[p1][c], w, a1);
    }
    Pout[(n0 + p0) * 128 + o2] = a0;
    Pout[(n0 + p1) * 128 + o2] = a1;
}

// ---------------------------------------------------------------- stage-3 fused edge+pool
__global__ __launch_bounds__(256) void zpool_kernel(const float* __restrict__ P,
                                                    const int* __restrict__ idx,
                                                    const float* __restrict__ gsIn,
                                                    const float* __restrict__ g,
                                                    const float* __restrict__ b,
                                                    float* __restrict__ Xout) {
    __shared__ float saff[128];
    int tid = threadIdx.x;
    compute_affine(gsIn, g, b, saff, tid);
    __syncthreads();
    int gid = blockIdx.x * 256 + tid;
    int n = gid >> 6, o = gid & 63;
    float An = P[n * 128 + o];
    float Bn = P[n * 128 + 64 + o];
    float base = Bn - An;
    float mxz = -INFINITY, mnz = INFINITY;
#pragma unroll
    for (int kk = 0; kk < KNN; ++kk) {
        int m = idx[n * KNN + kk];
        float z = P[m * 128 + o] + base;
        mxz = fmaxf(mxz, z); mnz = fminf(mnz, z);
    }
    float sc = saff[o], sh = saff[64 + o];
    float v = (sc >= 0.f) ? mxz : mnz;
    Xout[gid] = lrelu(fmaf(v, sc, sh));
}

// ---------------------------------------------------------------- fused final MLP
__global__ __launch_bounds__(128) void mlp_kernel(const float* __restrict__ x1,
                                                  const float* __restrict__ x2,
                                                  const float* __restrict__ x3,
                                                  const float* __restrict__ W9at,
                                                  const float* __restrict__ b9a,
                                                  const float* __restrict__ W9bt,
                                                  const float* __restrict__ b9b,
                                                  float* __restrict__ out) {
    __shared__ float hs[8][128];
    int tid = threadIdx.x;
    int j = tid;
    int n0 = blockIdx.x * 8;
    float acc[8];
    float bj = b9a[j];
#pragma unroll
    for (int p = 0; p < 8; ++p) acc[p] = bj;
    for (int c = 0; c < 64; ++c) {
        float w = W9at[c * 128 + j];
#pragma unroll
        for (int p = 0; p < 8; ++p) acc[p] = fmaf(x1[(n0 + p) * 64 + c], w, acc[p]);
    }
    for (int c = 0; c < 64; ++c) {
        float w = W9at[(64 + c) * 128 + j];
#pragma unroll
        for (int p = 0; p < 8; ++p) acc[p] = fmaf(x2[(n0 + p) * 64 + c], w, acc[p]);
    }
    for (int c = 0; c < 64; ++c) {
        float w = W9at[(128 + c) * 128 + j];
#pragma unroll
        for (int p = 0; p < 8; ++p) acc[p] = fmaf(x3[(n0 + p) * 64 + c], w, acc[p]);
    }
#pragma unroll
    for (int p = 0; p < 8; ++p) hs[p][j] = fmaxf(acc[p], 0.f);
    __syncthreads();
    int p2 = tid >> 4, j2 = tid & 15;
    float a = b9b[j2];
    for (int c = 0; c < 128; ++c) a = fmaf(hs[p2][c], W9bt[c * 16 + j2], a);
    out[j2 * NPTS + n0 + p2] = a;
}

// ---------------------------------------------------------------- launch
extern "C" void kernel_launch(void* const* d_in, const int* in_sizes, int n_in,
                              void* d_out, int out_size, void* d_ws, size_t ws_size,
                              hipStream_t stream) {
    const float* x   = (const float*)d_in[0];
    const float* W1  = (const float*)d_in[2];
    const float* g1  = (const float*)d_in[3];
    const float* b1  = (const float*)d_in[4];
    const float* W2  = (const float*)d_in[5];
    const float* g2  = (const float*)d_in[6];
    const float* b2  = (const float*)d_in[7];
    const float* W3  = (const float*)d_in[8];
    const float* g3  = (const float*)d_in[9];
    const float* b3  = (const float*)d_in[10];
    const float* W4  = (const float*)d_in[11];
    const float* g4  = (const float*)d_in[12];
    const float* b4  = (const float*)d_in[13];
    const float* W5  = (const float*)d_in[14];
    const float* g5  = (const float*)d_in[15];
    const float* b5  = (const float*)d_in[16];
    const float* W9a = (const float*)d_in[17];
    const float* b9a = (const float*)d_in[18];
    const float* W9b = (const float*)d_in[19];
    const float* b9b = (const float*)d_in[20];
    float* out = (float*)d_out;

    char* ws = (char*)d_ws;
    int*    idx    = (int*)(ws + 0);                 // 655360
    float4* pk     = (float4*)(ws + 655360);         // 131072
    float*  P      = (float*)(ws + 786432);          // 4 MB
    float*  Mx     = (float*)(ws + 4980736);         // 2 MB
    float*  Mn     = (float*)(ws + 7077888);         // 2 MB
    float*  gsAll  = (float*)(ws + 9175040);         // 163840
    float*  x1b    = (float*)(ws + 9338880);         // 2 MB
    float*  x2b    = (float*)(ws + 11436032);        // 2 MB
    float*  x3b    = (float*)(ws + 13533184);        // 2 MB
    float*  Wt1    = (float*)(ws + 15630336);        // 34304
    float*  Wt3    = (float*)(ws + 15664640);        // 32768
    float*  Wt5    = (float*)(ws + 15697408);        // 32768
    float*  W9at   = (float*)(ws + 15730176);        // 98304
    float*  W9bt   = (float*)(ws + 15828480);        // 8192
    float*  theta  = (float*)(ws + 15836672);        // 32768
    int*    scount = (int*)(ws + 15869440);          // 32768
    int2*   surv   = (int2*)(ws + 15902208);         // 16.8 MB
    (void)ws_size; (void)in_sizes; (void)n_in; (void)out_size;

    float* gs1 = gsAll;
    float* gs2 = gsAll + 1 * NREP * 128;
    float* gs3 = gsAll + 2 * NREP * 128;
    float* gs4 = gsAll + 3 * NREP * 128;
    float* gs5 = gsAll + 4 * NREP * 128;

    prep_kernel<<<426, 256, 0, stream>>>(x, W1, W3, W5, W9a, W9b, pk, Wt1, Wt3, Wt5, W9at, W9bt, gsAll, scount);
    knn_theta_proj<<<1536, 256, 0, stream>>>(pk, theta, x, Wt1, P);
    knn_filter<<<(NPTS / 16) * NSLICE, 256, 0, stream>>>(pk, theta, scount, surv);
    knn_select_zsum<<<NPTS / 4, 256, 0, stream>>>(pk, scount, surv, idx, P, gs1);

    // stage 1
    conv_gemm_kernel<<<NPTS * KNN / 80, 256, 0, stream>>>(P, idx, gs1, g1, b1, W2, gs2, Mx, Mn);
    pool_proj_kernel<<<NPTS / 4, 256, 0, stream>>>(Mx, Mn, gs2, g2, b2, Wt3, x1b, P);

    // stage 2
    zsum_kernel<<<NPTS / 4, 256, 0, stream>>>(P, idx, gs3);
    conv_gemm_kernel<<<NPTS * KNN / 80, 256, 0, stream>>>(P, idx, gs3, g3, b3, W4, gs4, Mx, Mn);
    pool_proj_kernel<<<NPTS / 4, 256, 0, stream>>>(Mx, Mn, gs4, g4, b4, Wt5, x2b, P);

    // stage 3
    zsum_kernel<<<NPTS / 4, 256, 0, stream>>>(P, idx, gs5);
    zpool_kernel<<<NPTS * 64 / 256, 256, 0, stream>>>(P, idx, gs5, g5, b5, x3b);

    // final MLP
    mlp_kernel<<<NPTS / 8, 128, 0, stream>>>(x1b, x2b, x3b, W9at, b9a, W9bt, b9b, out);
}